// Round 3
// baseline (183.102 us; speedup 1.0000x reference)
//
#include <hip/hip_runtime.h>
#include <math.h>

#define A_ 64
#define T_ 32
#define B_ 64
#define V_ 12
#define D_ 512
#define TAUF 100.0f
#define BG 2               // b's per block

// K1: inverse L2 norms of all text (2048) and video (768) rows -> ws
__global__ void norm_kernel(const float* __restrict__ text,
                            const float* __restrict__ video,
                            float* __restrict__ inv)
{
    int r = blockIdx.x;
    const float* src = (r < A_ * T_) ? (text + (size_t)r * D_)
                                     : (video + (size_t)(r - A_ * T_) * D_);
    int tid = threadIdx.x; // 128 threads, one float4 each (512 floats)
    float4 x = ((const float4*)src)[tid];
    float ss = x.x * x.x + x.y * x.y + x.z * x.z + x.w * x.w;
    for (int m = 32; m >= 1; m >>= 1) ss += __shfl_xor(ss, m);
    __shared__ float red[2];
    if ((tid & 63) == 0) red[tid >> 6] = ss;
    __syncthreads();
    if (tid == 0) {
        float s = red[0] + red[1];
        inv[r] = 1.0f / fmaxf(sqrtf(s), 1e-6f);
    }
}

// K2: one block per (a, 2 consecutive b). 192 threads, no LDS staging.
// Dot phase: thread = (tile = tid/24, vv = tid%24 -> bq = vv/12, v = vv%12),
// computes L[tile*4 .. tile*4+3][v] for b = bg*2+bq. 5 global dwordx4 : 16 FMA.
__global__ __launch_bounds__(192, 6)
void fused_kernel(const float* __restrict__ text,
                  const float* __restrict__ video,
                  const int* __restrict__ mask,
                  const float* __restrict__ inv,
                  float* __restrict__ out)
{
    const int a   = blockIdx.y;
    const int bg  = blockIdx.x;          // 0..31
    const int tid = threadIdx.x;         // 0..191

    __shared__ float Lsh[BG][T_][V_];    // raw logits (normalized)
    __shared__ float v2t_sh[BG][V_];
    __shared__ float w2_sh[BG][T_];
    __shared__ float wv_sh[BG][V_];
    __shared__ float stats[BG][2];
    __shared__ float redD[BG][3];
    __shared__ int   msh[T_];

    if (tid < T_) msh[tid] = mask[a * T_ + tid];

    // ---- dot phase: all loads from global (L1/L2-cached), no staging ----
    {
        const int tile = tid / (BG * V_);          // 0..7
        const int vv   = tid - tile * (BG * V_);   // 0..23
        const int bq   = vv / V_;
        const int v    = vv - bq * V_;
        const int b    = bg * BG + bq;

        const float4* tp = (const float4*)(text + ((size_t)a * T_ + tile * 4) * D_);
        const float4* vp = (const float4*)(video + ((size_t)b * V_ + v) * D_);
        float4 c0 = {0,0,0,0}, c1 = {0,0,0,0}, c2 = {0,0,0,0}, c3 = {0,0,0,0};
        #pragma unroll 2
        for (int k = 0; k < 128; ++k) {
            float4 y  = vp[k];
            float4 x0 = tp[k];
            float4 x1 = tp[k + 128];
            float4 x2 = tp[k + 256];
            float4 x3 = tp[k + 384];
            c0.x += x0.x * y.x; c0.y += x0.y * y.y; c0.z += x0.z * y.z; c0.w += x0.w * y.w;
            c1.x += x1.x * y.x; c1.y += x1.y * y.y; c1.z += x1.z * y.z; c1.w += x1.w * y.w;
            c2.x += x2.x * y.x; c2.y += x2.y * y.y; c2.z += x2.z * y.z; c2.w += x2.w * y.w;
            c3.x += x3.x * y.x; c3.y += x3.y * y.y; c3.z += x3.z * y.z; c3.w += x3.w * y.w;
        }
        const float* invt = inv + a * T_ + tile * 4;
        const float  iv   = inv[A_ * T_ + b * V_ + v];
        Lsh[bq][tile * 4 + 0][v] = ((c0.x + c0.y) + (c0.z + c0.w)) * invt[0] * iv;
        Lsh[bq][tile * 4 + 1][v] = ((c1.x + c1.y) + (c1.z + c1.w)) * invt[1] * iv;
        Lsh[bq][tile * 4 + 2][v] = ((c2.x + c2.y) + (c2.z + c2.w)) * invt[2] * iv;
        Lsh[bq][tile * 4 + 3][v] = ((c3.x + c3.y) + (c3.z + c3.w)) * invt[3] * iv;
    }
    __syncthreads();

    // ---- Phase B: row softmax -> t2v (reg); column masked softmax -> v2t_sh ----
    float t2v_val = 0.0f;
    if (tid < 64) {
        int bq2 = tid >> 5, t2 = tid & 31;
        const float* Lr = Lsh[bq2][t2];
        float l[V_];
        #pragma unroll
        for (int j = 0; j < V_; ++j) l[j] = Lr[j];
        if (msh[t2]) {
            float m = -1e30f;
            #pragma unroll
            for (int j = 0; j < V_; ++j) m = fmaxf(m, l[j]);
            float s = 0.f, num = 0.f;
            #pragma unroll
            for (int j = 0; j < V_; ++j) {
                float e = expf(TAUF * (l[j] - m));
                s += e; num += e * l[j];
            }
            t2v_val = num / s;
        } else {
            // softmax of all-zero logits = uniform -> mean of raw logits
            float s = 0.f;
            #pragma unroll
            for (int j = 0; j < V_; ++j) s += l[j];
            t2v_val = s * (1.0f / V_);
        }
    } else if (tid < 64 + BG * V_) {
        int idx = tid - 64;
        int bq2 = idx / V_, v2 = idx - bq2 * V_;
        float m = -1e30f;
        for (int j = 0; j < T_; ++j) {
            float Lm = msh[j] ? Lsh[bq2][j][v2] : 0.0f;
            if (Lm != 0.0f) m = fmaxf(m, Lm);
        }
        float s = 0.f, num = 0.f;
        for (int j = 0; j < T_; ++j) {
            float Lraw = Lsh[bq2][j][v2];
            float Lm = msh[j] ? Lraw : 0.0f;
            if (Lm != 0.0f) {
                float e = expf(TAUF * (Lm - m));
                s += e; num += e * Lraw;
            }
        }
        v2t_sh[bq2][v2] = num / s;
    }
    __syncthreads();

    // ---- Phase C: tps2 weights (shuffle reduce over 32-lane halves) and vps2 weights ----
    if (tid < 64) {
        int bq2 = tid >> 5, t2 = tid & 31;
        bool ex = (t2v_val == 0.0f);
        float x = ex ? -1e30f : t2v_val;
        #pragma unroll
        for (int m = 16; m >= 1; m >>= 1) x = fmaxf(x, __shfl_xor(x, m));
        float w = ex ? 0.0f : expf(TAUF * (t2v_val - x));
        float s = w;
        #pragma unroll
        for (int m = 16; m >= 1; m >>= 1) s += __shfl_xor(s, m);
        w2_sh[bq2][t2] = w;
        if (t2 == 0) stats[bq2][0] = s;
    } else if (tid < 64 + BG * V_) {
        int idx = tid - 64;
        int bq2 = idx / V_, v2 = idx - bq2 * V_;
        float m = -1e30f;
        #pragma unroll
        for (int j = 0; j < V_; ++j) m = fmaxf(m, v2t_sh[bq2][j]);
        float s = 0.f;
        #pragma unroll
        for (int j = 0; j < V_; ++j) s += expf(TAUF * (v2t_sh[bq2][j] - m));
        wv_sh[bq2][v2] = expf(TAUF * (v2t_sh[bq2][v2] - m));
        if (v2 == 0) stats[bq2][1] = s;
    }
    __syncthreads();

    // ---- Phase D: out[bq] = sum_{t,v} w2[t]*wv[v]*L[t,v] / (W2*Wv) ----
    {
        int t  = tid & 31;
        int hv = tid >> 5;               // 0..5 across 3 waves (two halves each)
        float p0 = w2_sh[0][t] * (wv_sh[0][hv]     * Lsh[0][t][hv]
                                + wv_sh[0][hv + 6] * Lsh[0][t][hv + 6]);
        float p1 = w2_sh[1][t] * (wv_sh[1][hv]     * Lsh[1][t][hv]
                                + wv_sh[1][hv + 6] * Lsh[1][t][hv + 6]);
        #pragma unroll
        for (int m = 32; m >= 1; m >>= 1) {
            p0 += __shfl_xor(p0, m);
            p1 += __shfl_xor(p1, m);
        }
        if ((tid & 63) == 0) {
            int w = tid >> 6;            // 0..2
            redD[0][w] = p0;
            redD[1][w] = p1;
        }
    }
    __syncthreads();
    if (tid < BG) {
        float s = redD[tid][0] + redD[tid][1] + redD[tid][2];
        out[a * B_ + bg * BG + tid] = s / (stats[tid][0] * stats[tid][1]);
    }
}

extern "C" void kernel_launch(void* const* d_in, const int* in_sizes, int n_in,
                              void* d_out, int out_size, void* d_ws, size_t ws_size,
                              hipStream_t stream) {
    const float* text  = (const float*)d_in[0];
    const float* video = (const float*)d_in[1];
    const int*   mask  = (const int*)d_in[2];
    float* out = (float*)d_out;
    float* inv = (float*)d_ws;   // 2816 floats

    norm_kernel<<<A_ * T_ + B_ * V_, 128, 0, stream>>>(text, video, inv);
    fused_kernel<<<dim3(B_ / BG, A_), 192, 0, stream>>>(text, video, mask, inv, out);
}

// Round 4
// 110.941 us; speedup vs baseline: 1.6504x; 1.6504x over previous
//
#include <hip/hip_runtime.h>
#include <math.h>

#define A_ 64
#define T_ 32
#define B_ 64
#define V_ 12
#define D_ 512
#define TAUF 100.0f
#define VSTRIDE (D_ + 4)   // 516 floats: v-lane aliasing is 2-way (free)

// K1: inverse L2 norms of all text (2048) and video (768) rows -> ws
__global__ void norm_kernel(const float* __restrict__ text,
                            const float* __restrict__ video,
                            float* __restrict__ inv)
{
    int r = blockIdx.x;
    const float* src = (r < A_ * T_) ? (text + (size_t)r * D_)
                                     : (video + (size_t)(r - A_ * T_) * D_);
    int tid = threadIdx.x; // 128 threads, one float4 each (512 floats)
    float4 x = ((const float4*)src)[tid];
    float ss = x.x * x.x + x.y * x.y + x.z * x.z + x.w * x.w;
    for (int m = 32; m >= 1; m >>= 1) ss += __shfl_xor(ss, m);
    __shared__ float red[2];
    if ((tid & 63) == 0) red[tid >> 6] = ss;
    __syncthreads();
    if (tid == 0) {
        float s = red[0] + red[1];
        inv[r] = 1.0f / fmaxf(sqrtf(s), 1e-6f);
    }
}

// K2: one block per (a,b). 192 threads = 16 t-pairs x 12 v.
// Per k-iter: 1 ds_read_b128 (video, LDS) + 2 global float4 (text, L1
// broadcast across the 12 v-lanes) + 8 FMA-instrs.
__global__ __launch_bounds__(192)
void fused_kernel(const float* __restrict__ text,
                  const float* __restrict__ video,
                  const int* __restrict__ mask,
                  const float* __restrict__ inv,
                  float* __restrict__ out)
{
    const int a   = blockIdx.y;
    const int b   = blockIdx.x;
    const int tid = threadIdx.x;      // 0..191

    __shared__ __align__(16) float vsh[V_][VSTRIDE];  // video, pre-scaled by inv norm
    __shared__ float Lsh[T_][V_];                     // raw (normalized) logits
    __shared__ float v2t_sh[V_];
    __shared__ float w2_sh[T_];
    __shared__ float wv_sh[V_];
    __shared__ float stats[2];
    __shared__ float redD[3];
    __shared__ int   msh[T_];

    // ---- stage video rows (scaled by inv norm) into LDS: 1536 float4, 8/thread ----
    {
        const float4* vbase = (const float4*)(video + (size_t)b * V_ * D_);
        const float*  invv  = inv + A_ * T_ + b * V_;
        #pragma unroll
        for (int k = 0; k < 8; ++k) {
            int idx = k * 192 + tid;      // 0..1535
            int row = idx >> 7;           // 0..11
            int col = idx & 127;          // 0..127
            float4 x = vbase[idx];
            float s = invv[row];
            x.x *= s; x.y *= s; x.z *= s; x.w *= s;
            *(float4*)&vsh[row][col * 4] = x;
        }
        if (tid < T_) msh[tid] = mask[a * T_ + tid];
    }
    __syncthreads();

    const int tg = tid / V_;              // 0..15 (t-pair)
    const int v  = tid - tg * V_;         // 0..11
    const int t0 = tg * 2;

    // ---- dot phase ----
    {
        const float4* tp = (const float4*)(text + ((size_t)a * T_ + t0) * D_);
        const float4* vp = (const float4*)&vsh[v][0];
        float4 c0 = {0,0,0,0}, c1 = {0,0,0,0};
        #pragma unroll 4
        for (int k = 0; k < 128; ++k) {
            float4 y  = vp[k];
            float4 x0 = tp[k];
            float4 x1 = tp[k + 128];      // next text row (contiguous)
            c0.x += x0.x * y.x; c0.y += x0.y * y.y; c0.z += x0.z * y.z; c0.w += x0.w * y.w;
            c1.x += x1.x * y.x; c1.y += x1.y * y.y; c1.z += x1.z * y.z; c1.w += x1.w * y.w;
        }
        const float* invt = inv + a * T_ + t0;
        Lsh[t0 + 0][v] = ((c0.x + c0.y) + (c0.z + c0.w)) * invt[0];
        Lsh[t0 + 1][v] = ((c1.x + c1.y) + (c1.z + c1.w)) * invt[1];
    }
    __syncthreads();

    // ---- Phase B: row softmax -> t2v (reg, lanes 0..31); column masked softmax -> v2t_sh ----
    float t2v_val = 0.0f;
    if (tid < T_) {
        const float* Lr = Lsh[tid];
        float l[V_];
        #pragma unroll
        for (int j = 0; j < V_; ++j) l[j] = Lr[j];
        if (msh[tid]) {
            float m = -1e30f;
            #pragma unroll
            for (int j = 0; j < V_; ++j) m = fmaxf(m, l[j]);
            float s = 0.f, num = 0.f;
            #pragma unroll
            for (int j = 0; j < V_; ++j) {
                float e = expf(TAUF * (l[j] - m));
                s += e; num += e * l[j];
            }
            t2v_val = num / s;
        } else {
            // masked row: softmax of zeros = uniform -> mean of raw logits
            float s = 0.f;
            #pragma unroll
            for (int j = 0; j < V_; ++j) s += l[j];
            t2v_val = s * (1.0f / V_);
        }
    } else if (tid >= 64 && tid < 64 + V_) {
        int vv = tid - 64;
        float m = -1e30f;
        for (int j = 0; j < T_; ++j) {
            float Lm = msh[j] ? Lsh[j][vv] : 0.0f;
            if (Lm != 0.0f) m = fmaxf(m, Lm);
        }
        float s = 0.f, num = 0.f;
        for (int j = 0; j < T_; ++j) {
            float Lraw = Lsh[j][vv];
            float Lm = msh[j] ? Lraw : 0.0f;
            if (Lm != 0.0f) {
                float e = expf(TAUF * (Lm - m));
                s += e; num += e * Lraw;
            }
        }
        v2t_sh[vv] = num / s;
    }
    __syncthreads();

    // ---- Phase C: tps2 weights (32-lane shuffle) and vps2 weights ----
    if (tid < T_) {
        bool ex = (t2v_val == 0.0f);
        float x = ex ? -1e30f : t2v_val;
        #pragma unroll
        for (int m = 16; m >= 1; m >>= 1) x = fmaxf(x, __shfl_xor(x, m));
        float w = ex ? 0.0f : expf(TAUF * (t2v_val - x));
        float s = w;
        #pragma unroll
        for (int m = 16; m >= 1; m >>= 1) s += __shfl_xor(s, m);
        w2_sh[tid] = w;
        if (tid == 0) stats[0] = s;
    } else if (tid >= 64 && tid < 64 + V_) {
        int vv = tid - 64;
        float m = -1e30f;
        #pragma unroll
        for (int j = 0; j < V_; ++j) m = fmaxf(m, v2t_sh[j]);
        float s = 0.f;
        #pragma unroll
        for (int j = 0; j < V_; ++j) s += expf(TAUF * (v2t_sh[j] - m));
        wv_sh[vv] = expf(TAUF * (v2t_sh[vv] - m));
        if (vv == 0) stats[1] = s;
    }
    __syncthreads();

    // ---- Phase D: out = sum_{t,v} w2[t]*wv[v]*L[t,v] / (W2*Wv) ----
    {
        int t  = tid & 31;
        int hv = tid >> 5;               // 0..5
        float p = w2_sh[t] * (wv_sh[hv]     * Lsh[t][hv]
                            + wv_sh[hv + 6] * Lsh[t][hv + 6]);
        #pragma unroll
        for (int m = 32; m >= 1; m >>= 1) p += __shfl_xor(p, m);
        if ((tid & 63) == 0) redD[tid >> 6] = p;
    }
    __syncthreads();
    if (tid == 0) {
        float s = redD[0] + redD[1] + redD[2];
        out[a * B_ + b] = s / (stats[0] * stats[1]);
    }
}

extern "C" void kernel_launch(void* const* d_in, const int* in_sizes, int n_in,
                              void* d_out, int out_size, void* d_ws, size_t ws_size,
                              hipStream_t stream) {
    const float* text  = (const float*)d_in[0];
    const float* video = (const float*)d_in[1];
    const int*   mask  = (const int*)d_in[2];
    float* out = (float*)d_out;
    float* inv = (float*)d_ws;   // 2816 floats

    norm_kernel<<<A_ * T_ + B_ * V_, 128, 0, stream>>>(text, video, inv);
    fused_kernel<<<dim3(B_, A_), 192, 0, stream>>>(text, video, mask, inv, out);
}

// Round 5
// 62.062 us; speedup vs baseline: 2.9503x; 1.7876x over previous
//
#include <hip/hip_runtime.h>
#include <math.h>

#define A_ 64
#define T_ 32
#define B_ 64
#define V_ 12
#define VP 16              // video rows padded to 16 per b (zeros) for MFMA N=16
#define D_ 512
#define TAUF 100.0f

typedef __attribute__((ext_vector_type(8))) short bf16x8;   // 8 bf16 = 4 VGPRs
typedef __attribute__((ext_vector_type(4))) float f32x4;

__device__ __forceinline__ unsigned short f2bf(float x) {
    unsigned int u = __float_as_uint(x);
    unsigned int r = (u + 0x7fffu + ((u >> 16) & 1u)) >> 16;   // RNE
    return (unsigned short)r;
}
__device__ __forceinline__ float bf2f(unsigned short h) {
    return __uint_as_float(((unsigned int)h) << 16);
}

// K1: per row: L2-normalize, split into bf16 hi + lo, write to ws.
// Blocks 0..2047: text rows. Blocks 2048..3071: padded video rows (b*16+v);
// v>=12 rows are zero-filled.
__global__ void prep_kernel(const float* __restrict__ text,
                            const float* __restrict__ video,
                            unsigned short* __restrict__ th,
                            unsigned short* __restrict__ tl,
                            unsigned short* __restrict__ vh,
                            unsigned short* __restrict__ vl)
{
    const int r = blockIdx.x;
    const int tid = threadIdx.x;          // 128 threads, one float4 each
    const float* src;
    unsigned short *dhi, *dlo;

    if (r < A_ * T_) {
        src = text + (size_t)r * D_;
        dhi = th + (size_t)r * D_;
        dlo = tl + (size_t)r * D_;
    } else {
        int vr = r - A_ * T_;             // padded row index = b*16 + v
        int b = vr >> 4, v = vr & 15;
        dhi = vh + (size_t)vr * D_;
        dlo = vl + (size_t)vr * D_;
        if (v >= V_) {                    // zero pad rows (block-uniform branch)
            ushort4 z = {0, 0, 0, 0};
            ((ushort4*)dhi)[tid] = z;
            ((ushort4*)dlo)[tid] = z;
            return;
        }
        src = video + ((size_t)b * V_ + v) * D_;
    }

    float4 x = ((const float4*)src)[tid];
    float ss = x.x * x.x + x.y * x.y + x.z * x.z + x.w * x.w;
    #pragma unroll
    for (int m = 32; m >= 1; m >>= 1) ss += __shfl_xor(ss, m);
    __shared__ float red[2];
    if ((tid & 63) == 0) red[tid >> 6] = ss;
    __syncthreads();
    float inv = 1.0f / fmaxf(sqrtf(red[0] + red[1]), 1e-6f);

    float y0 = x.x * inv, y1 = x.y * inv, y2 = x.z * inv, y3 = x.w * inv;
    ushort4 hh, ll;
    hh.x = f2bf(y0); hh.y = f2bf(y1); hh.z = f2bf(y2); hh.w = f2bf(y3);
    ll.x = f2bf(y0 - bf2f(hh.x));
    ll.y = f2bf(y1 - bf2f(hh.y));
    ll.z = f2bf(y2 - bf2f(hh.z));
    ll.w = f2bf(y3 - bf2f(hh.w));
    ((ushort4*)dhi)[tid] = hh;
    ((ushort4*)dlo)[tid] = ll;
}

// K2: one wave (64 threads) per (a,b).
// Logits via mfma_f32_16x16x32_bf16, bf16x3 split (hi*hi + hi*lo + lo*hi).
// A = normalized text rows (M=32 -> two 16-row tiles), B = normalized video
// rows (N=16, rows 12..15 zero). C layout: row=(lane>>4)*4+reg, col=lane&15.
__global__ __launch_bounds__(64)
void fused_kernel(const unsigned short* __restrict__ th,
                  const unsigned short* __restrict__ tl,
                  const unsigned short* __restrict__ vh,
                  const unsigned short* __restrict__ vl,
                  const int* __restrict__ mask,
                  float* __restrict__ out)
{
    const int a    = blockIdx.y;
    const int b    = blockIdx.x;
    const int lane = threadIdx.x;         // 0..63

    __shared__ float Lsh[T_][13];         // stride 13: conflict-free both axes
    __shared__ float v2t_sh[V_];
    __shared__ float w2_sh[T_];
    __shared__ float wv_sh[V_];
    __shared__ float stats[2];
    __shared__ int   msh[T_];

    if (lane < T_) msh[lane] = mask[a * T_ + lane];

    const int r16 = lane & 15;
    const int kg  = lane >> 4;            // k-group 0..3
    const size_t aoff0 = ((size_t)(a * T_ + r16)) * D_ + kg * 8;
    const size_t aoff1 = aoff0 + (size_t)16 * D_;
    const size_t boff  = ((size_t)(b * VP + r16)) * D_ + kg * 8;

    f32x4 acc0 = {0.f, 0.f, 0.f, 0.f};
    f32x4 acc1 = {0.f, 0.f, 0.f, 0.f};

    #pragma unroll
    for (int kk = 0; kk < D_; kk += 32) {
        bf16x8 a0h = *(const bf16x8*)(th + aoff0 + kk);
        bf16x8 a0l = *(const bf16x8*)(tl + aoff0 + kk);
        bf16x8 a1h = *(const bf16x8*)(th + aoff1 + kk);
        bf16x8 a1l = *(const bf16x8*)(tl + aoff1 + kk);
        bf16x8 bh  = *(const bf16x8*)(vh + boff + kk);
        bf16x8 bl  = *(const bf16x8*)(vl + boff + kk);
        acc0 = __builtin_amdgcn_mfma_f32_16x16x32_bf16(a0h, bh, acc0, 0, 0, 0);
        acc1 = __builtin_amdgcn_mfma_f32_16x16x32_bf16(a1h, bh, acc1, 0, 0, 0);
        acc0 = __builtin_amdgcn_mfma_f32_16x16x32_bf16(a0h, bl, acc0, 0, 0, 0);
        acc1 = __builtin_amdgcn_mfma_f32_16x16x32_bf16(a1h, bl, acc1, 0, 0, 0);
        acc0 = __builtin_amdgcn_mfma_f32_16x16x32_bf16(a0l, bh, acc0, 0, 0, 0);
        acc1 = __builtin_amdgcn_mfma_f32_16x16x32_bf16(a1l, bh, acc1, 0, 0, 0);
    }

    if (r16 < V_) {
        #pragma unroll
        for (int r = 0; r < 4; ++r) {
            Lsh[kg * 4 + r][r16]      = acc0[r];
            Lsh[16 + kg * 4 + r][r16] = acc1[r];
        }
    }
    __syncthreads();

    // ---- Phase B: lanes 0..31 row softmax -> t2v (reg);
    //      lanes 32..43 column masked softmax -> v2t_sh ----
    float t2v_val = 0.0f;
    if (lane < T_) {
        const float* Lr = Lsh[lane];
        float l[V_];
        #pragma unroll
        for (int j = 0; j < V_; ++j) l[j] = Lr[j];
        if (msh[lane]) {
            float m = -1e30f;
            #pragma unroll
            for (int j = 0; j < V_; ++j) m = fmaxf(m, l[j]);
            float s = 0.f, num = 0.f;
            #pragma unroll
            for (int j = 0; j < V_; ++j) {
                float e = expf(TAUF * (l[j] - m));
                s += e; num += e * l[j];
            }
            t2v_val = num / s;
        } else {
            // masked row: softmax of zeros = uniform -> mean of raw logits
            float s = 0.f;
            #pragma unroll
            for (int j = 0; j < V_; ++j) s += l[j];
            t2v_val = s * (1.0f / V_);
        }
    } else if (lane < T_ + V_) {
        int vv = lane - T_;
        float m = -1e30f;
        for (int j = 0; j < T_; ++j) {
            float Lm = msh[j] ? Lsh[j][vv] : 0.0f;
            if (Lm != 0.0f) m = fmaxf(m, Lm);
        }
        float s = 0.f, num = 0.f;
        for (int j = 0; j < T_; ++j) {
            float Lraw = Lsh[j][vv];
            float Lm = msh[j] ? Lraw : 0.0f;
            if (Lm != 0.0f) {
                float e = expf(TAUF * (Lm - m));
                s += e; num += e * Lraw;
            }
        }
        v2t_sh[vv] = num / s;
    }
    __syncthreads();

    // ---- Phase C: tps2 weights (width-32 shuffle reduce) and vps2 weights ----
    if (lane < T_) {
        bool ex = (t2v_val == 0.0f);
        float x = ex ? -1e30f : t2v_val;
        #pragma unroll
        for (int m = 16; m >= 1; m >>= 1) x = fmaxf(x, __shfl_xor(x, m));
        float w = ex ? 0.0f : expf(TAUF * (t2v_val - x));
        float s = w;
        #pragma unroll
        for (int m = 16; m >= 1; m >>= 1) s += __shfl_xor(s, m);
        w2_sh[lane] = w;
        if (lane == 0) stats[0] = s;
    } else if (lane < T_ + V_) {
        int vv = lane - T_;
        float m = -1e30f;
        #pragma unroll
        for (int j = 0; j < V_; ++j) m = fmaxf(m, v2t_sh[j]);
        float s = 0.f;
        #pragma unroll
        for (int j = 0; j < V_; ++j) s += expf(TAUF * (v2t_sh[j] - m));
        wv_sh[vv] = expf(TAUF * (v2t_sh[vv] - m));
        if (vv == 0) stats[1] = s;
    }
    __syncthreads();

    // ---- Phase D: out = sum_{t,v} w2[t]*wv[v]*L[t,v] / (W2*Wv) ----
    {
        int t  = lane & 31;
        int vg = lane >> 5;               // 0..1, each sums 6 v's
        float p = 0.f;
        #pragma unroll
        for (int j = 0; j < 6; ++j)
            p += wv_sh[vg * 6 + j] * Lsh[t][vg * 6 + j];
        p *= w2_sh[t];
        #pragma unroll
        for (int m = 32; m >= 1; m >>= 1) p += __shfl_xor(p, m);
        if (lane == 0) out[a * B_ + b] = p / (stats[0] * stats[1]);
    }
}

extern "C" void kernel_launch(void* const* d_in, const int* in_sizes, int n_in,
                              void* d_out, int out_size, void* d_ws, size_t ws_size,
                              hipStream_t stream) {
    const float* text  = (const float*)d_in[0];
    const float* video = (const float*)d_in[1];
    const int*   mask  = (const int*)d_in[2];
    float* out = (float*)d_out;

    unsigned short* th = (unsigned short*)d_ws;            // 2048*512
    unsigned short* tl = th + (size_t)A_ * T_ * D_;        // 2048*512
    unsigned short* vh = tl + (size_t)A_ * T_ * D_;        // 64*16*512
    unsigned short* vl = vh + (size_t)B_ * VP * D_;        // 64*16*512
    // total: 6,291,456 bytes of ws

    prep_kernel<<<A_ * T_ + B_ * VP, 128, 0, stream>>>(text, video, th, tl, vh, vl);
    fused_kernel<<<dim3(B_, A_), 64, 0, stream>>>(th, tl, vh, vl, mask, out);
}

// Round 7
// 32.956 us; speedup vs baseline: 5.5560x; 1.8832x over previous
//
#include <hip/hip_runtime.h>
#include <math.h>

#define A_ 64
#define T_ 32
#define B_ 64
#define V_ 12
#define D_ 512
#define TAUF 100.0f

#define BM 64              // M rows per block = 2 a
#define BN 48              // N cols per block = 4 b (packed, no padding)
#define BK 32              // K chunk
#define NCH (D_ / BK)      // 16 chunks
// One staging buffer (bytes): A_hi[kg][64][8] = 4096 | A_lo = 4096 |
// B_hi[kg][48][8] = 3072 | B_lo = 3072  -> 14336 B
#define ABYTES 4096
#define BBYTES 3072
#define BUFBYTES 14336

typedef __attribute__((ext_vector_type(8))) short bf16x8;
typedef __attribute__((ext_vector_type(4))) float f32x4;

__device__ __forceinline__ unsigned short f2bf(float x) {
    unsigned int u = __float_as_uint(x);
    unsigned int r = (u + 0x7fffu + ((u >> 16) & 1u)) >> 16;   // RNE
    return (unsigned short)r;
}
__device__ __forceinline__ float bf2f(unsigned short h) {
    return __uint_as_float(((unsigned int)h) << 16);
}

// K1: per row: L2-normalize, split into bf16 hi + lo, write to ws.
// Rows 0..2047: text. Rows 2048..2815: video (packed, row = b*12+v).
__global__ void prep_kernel(const float* __restrict__ text,
                            const float* __restrict__ video,
                            unsigned short* __restrict__ th,
                            unsigned short* __restrict__ tl,
                            unsigned short* __restrict__ vh,
                            unsigned short* __restrict__ vl)
{
    const int r = blockIdx.x;
    const int tid = threadIdx.x;          // 128 threads, one float4 each
    const float* src;
    unsigned short *dhi, *dlo;
    if (r < A_ * T_) {
        src = text + (size_t)r * D_;
        dhi = th + (size_t)r * D_;
        dlo = tl + (size_t)r * D_;
    } else {
        int vr = r - A_ * T_;
        src = video + (size_t)vr * D_;
        dhi = vh + (size_t)vr * D_;
        dlo = vl + (size_t)vr * D_;
    }
    float4 x = ((const float4*)src)[tid];
    float ss = x.x * x.x + x.y * x.y + x.z * x.z + x.w * x.w;
    #pragma unroll
    for (int m = 32; m >= 1; m >>= 1) ss += __shfl_xor(ss, m);
    __shared__ float red[2];
    if ((tid & 63) == 0) red[tid >> 6] = ss;
    __syncthreads();
    float inv = 1.0f / fmaxf(sqrtf(red[0] + red[1]), 1e-6f);

    float y0 = x.x * inv, y1 = x.y * inv, y2 = x.z * inv, y3 = x.w * inv;
    ushort4 hh, ll;
    hh.x = f2bf(y0); hh.y = f2bf(y1); hh.z = f2bf(y2); hh.w = f2bf(y3);
    ll.x = f2bf(y0 - bf2f(hh.x));
    ll.y = f2bf(y1 - bf2f(hh.y));
    ll.z = f2bf(y2 - bf2f(hh.z));
    ll.w = f2bf(y3 - bf2f(hh.w));
    ((ushort4*)dhi)[tid] = hh;
    ((ushort4*)dlo)[tid] = ll;
}

// K2: block = 64x48 C-tile (2 a x 4 b), 4 waves, dbuf global_load_lds staging.
// Wave wid owns M-strip rows [wid*16, wid*16+16) x 3 col-tiles of 16.
// mfma_f32_16x16x32_bf16, split hi*hi + hi*lo + lo*hi.
__global__ __launch_bounds__(256)
void fused_kernel(const unsigned short* __restrict__ th,
                  const unsigned short* __restrict__ tl,
                  const unsigned short* __restrict__ vh,
                  const unsigned short* __restrict__ vl,
                  const int* __restrict__ mask,
                  float* __restrict__ out)
{
    const int bn  = blockIdx.x;       // 0..15  (N tile: 4 b's)
    const int bm  = blockIdx.y;       // 0..31  (M tile: 2 a's)
    const int tid = threadIdx.x;      // 0..255
    const int wid = tid >> 6;         // 0..3
    const int lane = tid & 63;
    const int r16 = lane & 15;
    const int kg4 = lane >> 4;        // 0..3

    __shared__ __align__(16) char stage[2][BUFBYTES];
    __shared__ int   msh[2][T_];
    __shared__ float v2t_sh[8][V_];
    __shared__ float wv_sh[8][V_];
    __shared__ float stats1[8];

    if (tid < 64) msh[tid >> 5][tid & 31] = mask[(bm * 2 + (tid >> 5)) * T_ + (tid & 31)];

    // ---- per-lane global source base pointers for the 4 staging rounds ----
    // granule g in [0,896): g*16 bytes into the buffer.
    //   g<256: A_hi (row=g&63, kg=g>>6); g<512: A_lo; g<704: B_hi (h=g-512,
    //   kg=h/48,row=h%48); else B_lo.
    auto src_for = [&](int g) -> const unsigned short* {
        if (g < 256)      { int row = g & 63, kg = g >> 6;
                            return th + ((size_t)(bm * BM + row)) * D_ + kg * 8; }
        else if (g < 512) { int h = g - 256; int row = h & 63, kg = h >> 6;
                            return tl + ((size_t)(bm * BM + row)) * D_ + kg * 8; }
        else if (g < 704) { int h = g - 512; int kg = h / 48, row = h - kg * 48;
                            return vh + ((size_t)(bn * BN + row)) * D_ + kg * 8; }
        else              { int h = g - 704; int kg = h / 48, row = h - kg * 48;
                            return vl + ((size_t)(bn * BN + row)) * D_ + kg * 8; }
    };
    const unsigned short* s0 = src_for(0 * 256 + wid * 64 + lane);
    const unsigned short* s1 = src_for(1 * 256 + wid * 64 + lane);
    const unsigned short* s2 = src_for(2 * 256 + wid * 64 + lane);
    const unsigned short* s3 = (wid < 2) ? src_for(3 * 256 + wid * 64 + lane) : s0;

    #define GLD16(srcp, kk, off) \
        __builtin_amdgcn_global_load_lds( \
            (const __attribute__((address_space(1))) unsigned int*)((srcp) + (kk)), \
            (__attribute__((address_space(3))) unsigned int*)(&stage[bufi][off]), 16, 0, 0)

    auto STAGE = [&](int bufi, int kk) {
        GLD16(s0, kk, 0 * 4096 + wid * 1024);
        GLD16(s1, kk, 1 * 4096 + wid * 1024);
        GLD16(s2, kk, 2 * 4096 + wid * 1024);
        if (wid < 2) GLD16(s3, kk, 3 * 4096 + wid * 1024);
    };

    // fragment byte offsets within a buffer (2-way bank aliasing = free)
    const int aoff  = (kg4 * 64 + wid * 16 + r16) * 16;
    const int boff0 = 2 * ABYTES + (kg4 * 48 + 0 * 16 + r16) * 16;
    const int boff1 = 2 * ABYTES + (kg4 * 48 + 1 * 16 + r16) * 16;
    const int boff2 = 2 * ABYTES + (kg4 * 48 + 2 * 16 + r16) * 16;

    f32x4 acc0 = {0.f, 0.f, 0.f, 0.f};
    f32x4 acc1 = {0.f, 0.f, 0.f, 0.f};
    f32x4 acc2 = {0.f, 0.f, 0.f, 0.f};

    STAGE(0, 0);
    __syncthreads();

    #pragma unroll 2
    for (int k = 0; k < NCH; ++k) {
        if (k + 1 < NCH) {
            int bufi = (k + 1) & 1;
            STAGE(bufi, (k + 1) * BK);
        }
        const char* buf = stage[k & 1];
        bf16x8 aH  = *(const bf16x8*)(buf + aoff);
        bf16x8 aL  = *(const bf16x8*)(buf + ABYTES + aoff);
        bf16x8 bH0 = *(const bf16x8*)(buf + boff0);
        bf16x8 bL0 = *(const bf16x8*)(buf + BBYTES + boff0);
        bf16x8 bH1 = *(const bf16x8*)(buf + boff1);
        bf16x8 bL1 = *(const bf16x8*)(buf + BBYTES + boff1);
        bf16x8 bH2 = *(const bf16x8*)(buf + boff2);
        bf16x8 bL2 = *(const bf16x8*)(buf + BBYTES + boff2);
        acc0 = __builtin_amdgcn_mfma_f32_16x16x32_bf16(aH, bH0, acc0, 0, 0, 0);
        acc1 = __builtin_amdgcn_mfma_f32_16x16x32_bf16(aH, bH1, acc1, 0, 0, 0);
        acc2 = __builtin_amdgcn_mfma_f32_16x16x32_bf16(aH, bH2, acc2, 0, 0, 0);
        acc0 = __builtin_amdgcn_mfma_f32_16x16x32_bf16(aH, bL0, acc0, 0, 0, 0);
        acc1 = __builtin_amdgcn_mfma_f32_16x16x32_bf16(aH, bL1, acc1, 0, 0, 0);
        acc2 = __builtin_amdgcn_mfma_f32_16x16x32_bf16(aH, bL2, acc2, 0, 0, 0);
        acc0 = __builtin_amdgcn_mfma_f32_16x16x32_bf16(aL, bH0, acc0, 0, 0, 0);
        acc1 = __builtin_amdgcn_mfma_f32_16x16x32_bf16(aL, bH1, acc1, 0, 0, 0);
        acc2 = __builtin_amdgcn_mfma_f32_16x16x32_bf16(aL, bH2, acc2, 0, 0, 0);
        __syncthreads();
    }

    // ---- scatter C into Lf[a_local][b_local][t][v] (overlays stage[0]) ----
    float* Lf = (float*)&stage[0][0];      // 8*32*12*4 = 12288 B <= 14336
    {
        // C layout: row = (lane>>4)*4 + reg, col = lane&15 (m89-verified)
        #pragma unroll
        for (int r = 0; r < 4; ++r) {
            int Mrow0 = wid * 16 + kg4 * 4 + r;
            int al = Mrow0 >> 5, t = Mrow0 & 31;
            int c0 = 0 * 16 + r16, c1 = 1 * 16 + r16, c2 = 2 * 16 + r16;
            int bl0 = c0 / 12, bl1 = c1 / 12, bl2 = c2 / 12;
            Lf[((al * 4 + bl0) * T_ + t) * V_ + (c0 - bl0 * 12)] = acc0[r];
            Lf[((al * 4 + bl1) * T_ + t) * V_ + (c1 - bl1 * 12)] = acc1[r];
            Lf[((al * 4 + bl2) * T_ + t) * V_ + (c2 - bl2 * 12)] = acc2[r];
        }
    }
    __syncthreads();

    // ---- softmax phases: half-wave (32 lanes) per (a_local, b_local) pair ----
    const int p   = tid >> 5;          // 0..7
    const int l32 = tid & 31;
    const int al  = p >> 2, bl = p & 3;
    const float* Lrow = &Lf[((al * 4 + bl) * T_ + l32) * V_];

    // B-row: vps1 row softmax -> t2v (register)
    float t2v_val;
    {
        float l[V_];
        #pragma unroll
        for (int j = 0; j < V_; ++j) l[j] = Lrow[j];
        if (msh[al][l32]) {
            float m = -1e30f;
            #pragma unroll
            for (int j = 0; j < V_; ++j) m = fmaxf(m, l[j]);
            float s = 0.f, num = 0.f;
            #pragma unroll
            for (int j = 0; j < V_; ++j) {
                float e = expf(TAUF * (l[j] - m));
                s += e; num += e * l[j];
            }
            t2v_val = num / s;
        } else {
            // masked row: softmax of zeros = uniform -> mean of raw logits
            float s = 0.f;
            #pragma unroll
            for (int j = 0; j < V_; ++j) s += l[j];
            t2v_val = s * (1.0f / V_);
        }
    }

    // C-row: tps2 weights via width-32 shuffles; keep w and W2 in registers
    bool  ex = (t2v_val == 0.0f);
    float xm = ex ? -1e30f : t2v_val;
    #pragma unroll
    for (int m = 16; m >= 1; m >>= 1) xm = fmaxf(xm, __shfl_xor(xm, m, 32));
    float w2 = ex ? 0.0f : expf(TAUF * (t2v_val - xm));
    float W2 = w2;
    #pragma unroll
    for (int m = 16; m >= 1; m >>= 1) W2 += __shfl_xor(W2, m, 32);

    // B-col: tps1 masked column softmax -> v2t_sh
    if (l32 < V_) {
        float m = -1e30f;
        for (int j = 0; j < T_; ++j) {
            float Lraw = Lf[((al * 4 + bl) * T_ + j) * V_ + l32];
            float Lm = msh[al][j] ? Lraw : 0.0f;
            if (Lm != 0.0f) m = fmaxf(m, Lm);
        }
        float s = 0.f, num = 0.f;
        for (int j = 0; j < T_; ++j) {
            float Lraw = Lf[((al * 4 + bl) * T_ + j) * V_ + l32];
            float Lm = msh[al][j] ? Lraw : 0.0f;
            if (Lm != 0.0f) {
                float e = expf(TAUF * (Lm - m));
                s += e; num += e * Lraw;
            }
        }
        v2t_sh[p][l32] = num / s;
    }
    __syncthreads();

    // C-col: vps2 weights
    if (l32 < V_) {
        float m = -1e30f;
        #pragma unroll
        for (int j = 0; j < V_; ++j) m = fmaxf(m, v2t_sh[p][j]);
        float s = 0.f;
        #pragma unroll
        for (int j = 0; j < V_; ++j) s += expf(TAUF * (v2t_sh[p][j] - m));
        wv_sh[p][l32] = expf(TAUF * (v2t_sh[p][l32] - m));
        if (l32 == 0) stats1[p] = s;
    }
    __syncthreads();

    // D: out = sum_{t,v} w2[t]*wv[v]*L[t,v] / (W2*Wv)
    {
        float pD = 0.f;
        #pragma unroll
        for (int j = 0; j < V_; ++j) pD += wv_sh[p][j] * Lrow[j];
        pD *= w2;
        #pragma unroll
        for (int m = 16; m >= 1; m >>= 1) pD += __shfl_xor(pD, m, 32);
        if (l32 == 0)
            out[(bm * 2 + al) * B_ + bn * 4 + bl] = pD / (W2 * stats1[p]);
    }
    #undef GLD16
}

extern "C" void kernel_launch(void* const* d_in, const int* in_sizes, int n_in,
                              void* d_out, int out_size, void* d_ws, size_t ws_size,
                              hipStream_t stream) {
    const float* text  = (const float*)d_in[0];
    const float* video = (const float*)d_in[1];
    const int*   mask  = (const int*)d_in[2];
    float* out = (float*)d_out;

    unsigned short* th = (unsigned short*)d_ws;            // 2048*512
    unsigned short* tl = th + (size_t)A_ * T_ * D_;        // 2048*512
    unsigned short* vh = tl + (size_t)A_ * T_ * D_;        // 768*512
    unsigned short* vl = vh + (size_t)B_ * V_ * D_;        // 768*512
    // total ws use: 5,767,168 bytes

    prep_kernel<<<A_ * T_ + B_ * V_, 128, 0, stream>>>(text, video, th, tl, vh, vl);
    fused_kernel<<<dim3(B_ * V_ / BN, A_ * T_ / BM), 256, 0, stream>>>(th, tl, vh, vl, mask, out);
}

// Round 8
// 32.455 us; speedup vs baseline: 5.6417x; 1.0154x over previous
//
#include <hip/hip_runtime.h>
#include <math.h>

#define A_ 64
#define T_ 32
#define B_ 64
#define V_ 12
#define D_ 512
#define TAUF 100.0f

#define BM 64              // M rows per block = 2 a
#define BN 48              // N cols per block = 4 b (packed)
#define BK 32              // K chunk
#define NCH 16             // 512 / 32
// packed per-(bm,k) A buffer: hi[kg][64][8] 4096B | lo 4096B  = 8192 B (4096 ush)
// packed per-(bn,k) B buffer: hi[kg][48][8] 3072B | lo 3072B  = 6144 B (3072 ush)
#define ABUF_USH 4096
#define BBUF_USH 3072
#define BUFBYTES 14336     // 8192 + 6144 per K-chunk stage

typedef __attribute__((ext_vector_type(8))) short bf16x8;
typedef __attribute__((ext_vector_type(4))) float f32x4;

__device__ __forceinline__ unsigned short f2bf(float x) {
    unsigned int u = __float_as_uint(x);
    unsigned int r = (u + 0x7fffu + ((u >> 16) & 1u)) >> 16;   // RNE
    return (unsigned short)r;
}
__device__ __forceinline__ float bf2f(unsigned short h) {
    return __uint_as_float(((unsigned int)h) << 16);
}

// K1: inverse L2 norms of all rows -> inv[2816] (text 0..2047, video 2048..2815)
__global__ void norm_kernel(const float* __restrict__ text,
                            const float* __restrict__ video,
                            float* __restrict__ inv)
{
    int r = blockIdx.x;
    const float* src = (r < A_ * T_) ? (text + (size_t)r * D_)
                                     : (video + (size_t)(r - A_ * T_) * D_);
    int tid = threadIdx.x; // 128 threads, one float4 each
    float4 x = ((const float4*)src)[tid];
    float ss = x.x * x.x + x.y * x.y + x.z * x.z + x.w * x.w;
    #pragma unroll
    for (int m = 32; m >= 1; m >>= 1) ss += __shfl_xor(ss, m);
    __shared__ float red[2];
    if ((tid & 63) == 0) red[tid >> 6] = ss;
    __syncthreads();
    if (tid == 0) inv[r] = 1.0f / fmaxf(sqrtf(red[0] + red[1]), 1e-6f);
}

// K2: normalize + bf16 hi/lo split + repack into the exact LDS staging image.
// Blocks 0..511: A buffers (bm = bi>>4, k = bi&15), granule p = kg*64+row.
// Blocks 512..767: B buffers (bn, k), granule p = kg*48+row.
// Writes are lane-contiguous 16B granules (fully coalesced).
__global__ __launch_bounds__(128)
void pack_kernel(const float* __restrict__ text,
                 const float* __restrict__ video,
                 const float* __restrict__ inv,
                 unsigned short* __restrict__ Apk,
                 unsigned short* __restrict__ Bpk)
{
    const int bi = blockIdx.x;
    const int t  = threadIdx.x;      // 0..127

    if (bi < 512) {
        const int bm = bi >> 4, k = bi & 15;
        unsigned short* outb = Apk + (size_t)(bm * 16 + k) * ABUF_USH;
        #pragma unroll
        for (int i = 0; i < 2; ++i) {
            int p = t + i * 128;                 // 0..255
            int kg = p >> 6, row = p & 63;
            int r = bm * 64 + row;
            const float* src = text + (size_t)r * D_ + k * 32 + kg * 8;
            float s = inv[r];
            float4 x0 = ((const float4*)src)[0];
            float4 x1 = ((const float4*)src)[1];
            float y0 = x0.x * s, y1 = x0.y * s, y2 = x0.z * s, y3 = x0.w * s;
            float y4 = x1.x * s, y5 = x1.y * s, y6 = x1.z * s, y7 = x1.w * s;
            ushort4 h0, h1, l0, l1;
            h0.x = f2bf(y0); h0.y = f2bf(y1); h0.z = f2bf(y2); h0.w = f2bf(y3);
            h1.x = f2bf(y4); h1.y = f2bf(y5); h1.z = f2bf(y6); h1.w = f2bf(y7);
            l0.x = f2bf(y0 - bf2f(h0.x)); l0.y = f2bf(y1 - bf2f(h0.y));
            l0.z = f2bf(y2 - bf2f(h0.z)); l0.w = f2bf(y3 - bf2f(h0.w));
            l1.x = f2bf(y4 - bf2f(h1.x)); l1.y = f2bf(y5 - bf2f(h1.y));
            l1.z = f2bf(y6 - bf2f(h1.z)); l1.w = f2bf(y7 - bf2f(h1.w));
            ((ushort4*)(outb + p * 8))[0] = h0;
            ((ushort4*)(outb + p * 8))[1] = h1;
            ((ushort4*)(outb + 2048 + p * 8))[0] = l0;
            ((ushort4*)(outb + 2048 + p * 8))[1] = l1;
        }
    } else {
        const int j = bi - 512;
        const int bn = j >> 4, k = j & 15;
        unsigned short* outb = Bpk + (size_t)(bn * 16 + k) * BBUF_USH;
        #pragma unroll
        for (int i = 0; i < 2; ++i) {
            int p = t + i * 128;                 // 0..255, valid < 192
            if (p >= 192) break;
            int kg = p / 48, row = p - kg * 48;
            int vr = bn * 48 + row;
            const float* src = video + (size_t)vr * D_ + k * 32 + kg * 8;
            float s = inv[A_ * T_ + vr];
            float4 x0 = ((const float4*)src)[0];
            float4 x1 = ((const float4*)src)[1];
            float y0 = x0.x * s, y1 = x0.y * s, y2 = x0.z * s, y3 = x0.w * s;
            float y4 = x1.x * s, y5 = x1.y * s, y6 = x1.z * s, y7 = x1.w * s;
            ushort4 h0, h1, l0, l1;
            h0.x = f2bf(y0); h0.y = f2bf(y1); h0.z = f2bf(y2); h0.w = f2bf(y3);
            h1.x = f2bf(y4); h1.y = f2bf(y5); h1.z = f2bf(y6); h1.w = f2bf(y7);
            l0.x = f2bf(y0 - bf2f(h0.x)); l0.y = f2bf(y1 - bf2f(h0.y));
            l0.z = f2bf(y2 - bf2f(h0.z)); l0.w = f2bf(y3 - bf2f(h0.w));
            l1.x = f2bf(y4 - bf2f(h1.x)); l1.y = f2bf(y5 - bf2f(h1.y));
            l1.z = f2bf(y6 - bf2f(h1.z)); l1.w = f2bf(y7 - bf2f(h1.w));
            ((ushort4*)(outb + p * 8))[0] = h0;
            ((ushort4*)(outb + p * 8))[1] = h1;
            ((ushort4*)(outb + 1536 + p * 8))[0] = l0;
            ((ushort4*)(outb + 1536 + p * 8))[1] = l1;
        }
    }
}

// K3: block = 64x48 C-tile (2 a x 4 b), 4 waves, dbuf global_load_lds staging
// from the packed image: every wave-load is 1 KB contiguous global memory.
__global__ __launch_bounds__(256)
void fused_kernel(const unsigned short* __restrict__ Apk,
                  const unsigned short* __restrict__ Bpk,
                  const int* __restrict__ mask,
                  float* __restrict__ out)
{
    const int bn  = blockIdx.x;       // 0..15
    const int bm  = blockIdx.y;       // 0..31
    const int tid = threadIdx.x;      // 0..255
    const int wid = tid >> 6;
    const int lane = tid & 63;
    const int r16 = lane & 15;
    const int kg4 = lane >> 4;

    __shared__ __align__(16) char stage[2][BUFBYTES];
    __shared__ int   msh[2][T_];
    __shared__ float v2t_sh[8][V_];
    __shared__ float wv_sh[8][V_];
    __shared__ float stats1[8];

    if (tid < 64) msh[tid >> 5][tid & 31] = mask[(bm * 2 + (tid >> 5)) * T_ + (tid & 31)];

    // per-thread packed sources (granule = tid within each region)
    const unsigned short* sA = Apk + (size_t)bm * 16 * ABUF_USH + tid * 8;
    const unsigned short* sB = Bpk + (size_t)bn * 16 * BBUF_USH + tid * 8;

    #define GLD16(srcp, off) \
        __builtin_amdgcn_global_load_lds( \
            (const __attribute__((address_space(1))) unsigned int*)(srcp), \
            (__attribute__((address_space(3))) unsigned int*)(&stage[bufi][off]), 16, 0, 0)

    auto STAGE = [&](int bufi, int k) {
        const unsigned short* a = sA + k * ABUF_USH;
        const unsigned short* bsrc = sB + k * BBUF_USH;
        GLD16(a,            0 * 4096 + wid * 1024);
        GLD16(a + 2048,     1 * 4096 + wid * 1024);
        GLD16(bsrc,         2 * 4096 + wid * 1024);
        if (wid < 2) GLD16(bsrc + 2048, 3 * 4096 + wid * 1024);
    };

    // fragment byte offsets within a stage buffer
    const int aoff  = (kg4 * 64 + wid * 16 + r16) * 16;
    const int boff0 = 8192 + (kg4 * 48 + 0 * 16 + r16) * 16;
    const int boff1 = 8192 + (kg4 * 48 + 1 * 16 + r16) * 16;
    const int boff2 = 8192 + (kg4 * 48 + 2 * 16 + r16) * 16;

    f32x4 acc0 = {0.f, 0.f, 0.f, 0.f};
    f32x4 acc1 = {0.f, 0.f, 0.f, 0.f};
    f32x4 acc2 = {0.f, 0.f, 0.f, 0.f};

    {
        int bufi = 0;
        STAGE(0, 0);
    }
    __syncthreads();

    #pragma unroll 2
    for (int k = 0; k < NCH; ++k) {
        if (k + 1 < NCH) {
            int bufi = (k + 1) & 1;
            STAGE(bufi, k + 1);
        }
        const char* buf = stage[k & 1];
        bf16x8 aH  = *(const bf16x8*)(buf + aoff);
        bf16x8 aL  = *(const bf16x8*)(buf + 4096 + aoff);
        bf16x8 bH0 = *(const bf16x8*)(buf + boff0);
        bf16x8 bL0 = *(const bf16x8*)(buf + 3072 + boff0);
        bf16x8 bH1 = *(const bf16x8*)(buf + boff1);
        bf16x8 bL1 = *(const bf16x8*)(buf + 3072 + boff1);
        bf16x8 bH2 = *(const bf16x8*)(buf + boff2);
        bf16x8 bL2 = *(const bf16x8*)(buf + 3072 + boff2);
        acc0 = __builtin_amdgcn_mfma_f32_16x16x32_bf16(aH, bH0, acc0, 0, 0, 0);
        acc1 = __builtin_amdgcn_mfma_f32_16x16x32_bf16(aH, bH1, acc1, 0, 0, 0);
        acc2 = __builtin_amdgcn_mfma_f32_16x16x32_bf16(aH, bH2, acc2, 0, 0, 0);
        acc0 = __builtin_amdgcn_mfma_f32_16x16x32_bf16(aH, bL0, acc0, 0, 0, 0);
        acc1 = __builtin_amdgcn_mfma_f32_16x16x32_bf16(aH, bL1, acc1, 0, 0, 0);
        acc2 = __builtin_amdgcn_mfma_f32_16x16x32_bf16(aH, bL2, acc2, 0, 0, 0);
        acc0 = __builtin_amdgcn_mfma_f32_16x16x32_bf16(aL, bH0, acc0, 0, 0, 0);
        acc1 = __builtin_amdgcn_mfma_f32_16x16x32_bf16(aL, bH1, acc1, 0, 0, 0);
        acc2 = __builtin_amdgcn_mfma_f32_16x16x32_bf16(aL, bH2, acc2, 0, 0, 0);
        __syncthreads();
    }

    // ---- scatter C into Lf[a_local][b_local][t][v] (overlays stage[0]) ----
    float* Lf = (float*)&stage[0][0];      // 12288 B
    {
        // C layout: row = (lane>>4)*4 + reg, col = lane&15
        #pragma unroll
        for (int r = 0; r < 4; ++r) {
            int Mrow0 = wid * 16 + kg4 * 4 + r;
            int al = Mrow0 >> 5, t = Mrow0 & 31;
            int c0 = 0 * 16 + r16, c1 = 1 * 16 + r16, c2 = 2 * 16 + r16;
            int bl0 = c0 / 12, bl1 = c1 / 12, bl2 = c2 / 12;
            Lf[((al * 4 + bl0) * T_ + t) * V_ + (c0 - bl0 * 12)] = acc0[r];
            Lf[((al * 4 + bl1) * T_ + t) * V_ + (c1 - bl1 * 12)] = acc1[r];
            Lf[((al * 4 + bl2) * T_ + t) * V_ + (c2 - bl2 * 12)] = acc2[r];
        }
    }
    __syncthreads();

    // ---- softmax phases: half-wave (32 lanes) per (a_local, b_local) pair ----
    const int p   = tid >> 5;          // 0..7
    const int l32 = tid & 31;
    const int al  = p >> 2, bl = p & 3;
    const float* Lrow = &Lf[((al * 4 + bl) * T_ + l32) * V_];

    // vps1 row softmax -> t2v (register)
    float t2v_val;
    {
        float l[V_];
        #pragma unroll
        for (int j = 0; j < V_; ++j) l[j] = Lrow[j];
        if (msh[al][l32]) {
            float m = -1e30f;
            #pragma unroll
            for (int j = 0; j < V_; ++j) m = fmaxf(m, l[j]);
            float s = 0.f, num = 0.f;
            #pragma unroll
            for (int j = 0; j < V_; ++j) {
                float e = expf(TAUF * (l[j] - m));
                s += e; num += e * l[j];
            }
            t2v_val = num / s;
        } else {
            // masked row: softmax of zeros = uniform -> mean of raw logits
            float s = 0.f;
            #pragma unroll
            for (int j = 0; j < V_; ++j) s += l[j];
            t2v_val = s * (1.0f / V_);
        }
    }

    // tps2 weights via width-32 shuffles; keep w2, W2 in registers
    bool  ex = (t2v_val == 0.0f);
    float xm = ex ? -1e30f : t2v_val;
    #pragma unroll
    for (int m = 16; m >= 1; m >>= 1) xm = fmaxf(xm, __shfl_xor(xm, m, 32));
    float w2 = ex ? 0.0f : expf(TAUF * (t2v_val - xm));
    float W2 = w2;
    #pragma unroll
    for (int m = 16; m >= 1; m >>= 1) W2 += __shfl_xor(W2, m, 32);

    // tps1 masked column softmax -> v2t_sh
    if (l32 < V_) {
        float m = -1e30f;
        for (int j = 0; j < T_; ++j) {
            float Lraw = Lf[((al * 4 + bl) * T_ + j) * V_ + l32];
            float Lm = msh[al][j] ? Lraw : 0.0f;
            if (Lm != 0.0f) m = fmaxf(m, Lm);
        }
        float s = 0.f, num = 0.f;
        for (int j = 0; j < T_; ++j) {
            float Lraw = Lf[((al * 4 + bl) * T_ + j) * V_ + l32];
            float Lm = msh[al][j] ? Lraw : 0.0f;
            if (Lm != 0.0f) {
                float e = expf(TAUF * (Lm - m));
                s += e; num += e * Lraw;
            }
        }
        v2t_sh[p][l32] = num / s;
    }
    __syncthreads();

    // vps2 weights
    if (l32 < V_) {
        float m = -1e30f;
        #pragma unroll
        for (int j = 0; j < V_; ++j) m = fmaxf(m, v2t_sh[p][j]);
        float s = 0.f;
        #pragma unroll
        for (int j = 0; j < V_; ++j) s += expf(TAUF * (v2t_sh[p][j] - m));
        wv_sh[p][l32] = expf(TAUF * (v2t_sh[p][l32] - m));
        if (l32 == 0) stats1[p] = s;
    }
    __syncthreads();

    // out = sum_{t,v} w2[t]*wv[v]*L[t,v] / (W2*Wv)
    {
        float pD = 0.f;
        #pragma unroll
        for (int j = 0; j < V_; ++j) pD += wv_sh[p][j] * Lrow[j];
        pD *= w2;
        #pragma unroll
        for (int m = 16; m >= 1; m >>= 1) pD += __shfl_xor(pD, m, 32);
        if (l32 == 0)
            out[(bm * 2 + al) * B_ + bn * 4 + bl] = pD / (W2 * stats1[p]);
    }
    #undef GLD16
}

extern "C" void kernel_launch(void* const* d_in, const int* in_sizes, int n_in,
                              void* d_out, int out_size, void* d_ws, size_t ws_size,
                              hipStream_t stream) {
    const float* text  = (const float*)d_in[0];
    const float* video = (const float*)d_in[1];
    const int*   mask  = (const int*)d_in[2];
    float* out = (float*)d_out;

    float* inv = (float*)d_ws;                                    // 2816 floats
    unsigned short* Apk = (unsigned short*)((char*)d_ws + 16384); // 32*16*4096 ush = 4 MB
    unsigned short* Bpk = Apk + (size_t)32 * 16 * ABUF_USH;       // 16*16*3072 ush = 1.5 MB

    norm_kernel<<<A_ * T_ + B_ * V_, 128, 0, stream>>>(text, video, inv);
    pack_kernel<<<768, 128, 0, stream>>>(text, video, inv, Apk, Bpk);
    fused_kernel<<<dim3(16, 32), 256, 0, stream>>>(Apk, Bpk, mask, out);
}

// Round 9
// 30.673 us; speedup vs baseline: 5.9694x; 1.0581x over previous
//
#include <hip/hip_runtime.h>
#include <math.h>

#define A_ 64
#define T_ 32
#define B_ 64
#define V_ 12
#define D_ 512
#define TAUF 100.0f

#define BM 64              // M rows per block = 2 a
#define BN 48              // N cols per block = 4 b (packed)
#define BK 32              // K chunk
#define NCH 16             // 512 / 32
// packed per-(bm,k) A buffer: hi[kg][64][8] 4096B | lo 4096B  = 8192 B (4096 ush)
// packed per-(bn,k) B buffer: hi[kg][48][8] 3072B | lo 3072B  = 6144 B (3072 ush)
#define ABUF_USH 4096
#define BBUF_USH 3072
#define BUFBYTES 14336     // 8192 + 6144 per K-chunk stage

typedef __attribute__((ext_vector_type(8))) short bf16x8;
typedef __attribute__((ext_vector_type(4))) float f32x4;

__device__ __forceinline__ unsigned short f2bf(float x) {
    unsigned int u = __float_as_uint(x);
    unsigned int r = (u + 0x7fffu + ((u >> 16) & 1u)) >> 16;   // RNE
    return (unsigned short)r;
}
__device__ __forceinline__ float bf2f(unsigned short h) {
    return __uint_as_float(((unsigned int)h) << 16);
}

// K1 (merged norm+pack): one wave per 4 rows. Full-wave shfl reduce gives the
// row norm to all 64 lanes (row = 64 lanes x 8 elems); each lane then splits
// its 8 elems into bf16 hi/lo and writes its 16B granule of the packed image.
// Blocks 0..511: text rows r = blk*4+rr. Blocks 512..703: video rows.
__global__ __launch_bounds__(64)
void pack_kernel(const float* __restrict__ text,
                 const float* __restrict__ video,
                 unsigned short* __restrict__ Apk,
                 unsigned short* __restrict__ Bpk)
{
    const int blk = blockIdx.x;
    const int l   = threadIdx.x;      // 0..63
    const int k   = l >> 2;           // k-chunk 0..15
    const int kg  = l & 3;            // k-group within chunk

    #pragma unroll
    for (int rr = 0; rr < 4; ++rr) {
        const float* src;
        unsigned short *obh, *obl;
        if (blk < 512) {
            int r = blk * 4 + rr;                 // 0..2047
            int bm = r >> 6, row = r & 63;
            src = text + (size_t)r * D_ + l * 8;
            unsigned short* base = Apk + ((size_t)(bm * 16 + k)) * ABUF_USH;
            obh = base + (kg * 64 + row) * 8;
            obl = obh + 2048;
        } else {
            int vr = (blk - 512) * 4 + rr;        // 0..767
            int bn = vr / 48, row = vr - bn * 48;
            src = video + (size_t)vr * D_ + l * 8;
            unsigned short* base = Bpk + ((size_t)(bn * 16 + k)) * BBUF_USH;
            obh = base + (kg * 48 + row) * 8;
            obl = obh + 1536;
        }
        float4 x0 = ((const float4*)src)[0];
        float4 x1 = ((const float4*)src)[1];
        float ss = x0.x * x0.x + x0.y * x0.y + x0.z * x0.z + x0.w * x0.w
                 + x1.x * x1.x + x1.y * x1.y + x1.z * x1.z + x1.w * x1.w;
        #pragma unroll
        for (int m = 32; m >= 1; m >>= 1) ss += __shfl_xor(ss, m);
        float inv = 1.0f / fmaxf(sqrtf(ss), 1e-6f);

        float y0 = x0.x * inv, y1 = x0.y * inv, y2 = x0.z * inv, y3 = x0.w * inv;
        float y4 = x1.x * inv, y5 = x1.y * inv, y6 = x1.z * inv, y7 = x1.w * inv;
        ushort4 h0, h1, l0, l1;
        h0.x = f2bf(y0); h0.y = f2bf(y1); h0.z = f2bf(y2); h0.w = f2bf(y3);
        h1.x = f2bf(y4); h1.y = f2bf(y5); h1.z = f2bf(y6); h1.w = f2bf(y7);
        l0.x = f2bf(y0 - bf2f(h0.x)); l0.y = f2bf(y1 - bf2f(h0.y));
        l0.z = f2bf(y2 - bf2f(h0.z)); l0.w = f2bf(y3 - bf2f(h0.w));
        l1.x = f2bf(y4 - bf2f(h1.x)); l1.y = f2bf(y5 - bf2f(h1.y));
        l1.z = f2bf(y6 - bf2f(h1.z)); l1.w = f2bf(y7 - bf2f(h1.w));
        ((ushort4*)obh)[0] = h0;
        ((ushort4*)obh)[1] = h1;
        ((ushort4*)obl)[0] = l0;
        ((ushort4*)obl)[1] = l1;
    }
}

// K2: block = 64x48 C-tile (2 a x 4 b), 4 waves, dbuf global_load_lds staging
// from the packed image (1 KB contiguous wave-loads). XCD-aware swizzle:
// each XCD owns 4 bm-panels x all 16 bn -> ~2 MB working set, L2-resident.
__global__ __launch_bounds__(256)
void fused_kernel(const unsigned short* __restrict__ Apk,
                  const unsigned short* __restrict__ Bpk,
                  const int* __restrict__ mask,
                  float* __restrict__ out)
{
    const int wgid = blockIdx.x;      // 0..511
    const int xcd  = wgid & 7;
    const int i    = wgid >> 3;       // 0..63
    const int bm   = xcd * 4 + (i >> 4);   // 0..31
    const int bn   = i & 15;               // 0..15
    const int tid = threadIdx.x;      // 0..255
    const int wid = tid >> 6;
    const int lane = tid & 63;
    const int r16 = lane & 15;
    const int kg4 = lane >> 4;

    __shared__ __align__(16) char stage[2][BUFBYTES];
    __shared__ int   msh[2][T_];
    __shared__ float v2t_sh[8][V_];
    __shared__ float wv_sh[8][V_];
    __shared__ float stats1[8];

    if (tid < 64) msh[tid >> 5][tid & 31] = mask[(bm * 2 + (tid >> 5)) * T_ + (tid & 31)];

    // per-thread packed sources (granule = tid within each region)
    const unsigned short* sA = Apk + (size_t)bm * 16 * ABUF_USH + tid * 8;
    const unsigned short* sB = Bpk + (size_t)bn * 16 * BBUF_USH + tid * 8;

    #define GLD16(srcp, off) \
        __builtin_amdgcn_global_load_lds( \
            (const __attribute__((address_space(1))) unsigned int*)(srcp), \
            (__attribute__((address_space(3))) unsigned int*)(&stage[bufi][off]), 16, 0, 0)

    auto STAGE = [&](int bufi, int k) {
        const unsigned short* a = sA + k * ABUF_USH;
        const unsigned short* bsrc = sB + k * BBUF_USH;
        GLD16(a,            0 * 4096 + wid * 1024);
        GLD16(a + 2048,     1 * 4096 + wid * 1024);
        GLD16(bsrc,         2 * 4096 + wid * 1024);
        if (wid < 2) GLD16(bsrc + 2048, 3 * 4096 + wid * 1024);
    };

    // fragment byte offsets within a stage buffer
    const int aoff  = (kg4 * 64 + wid * 16 + r16) * 16;
    const int boff0 = 8192 + (kg4 * 48 + 0 * 16 + r16) * 16;
    const int boff1 = 8192 + (kg4 * 48 + 1 * 16 + r16) * 16;
    const int boff2 = 8192 + (kg4 * 48 + 2 * 16 + r16) * 16;

    f32x4 acc0 = {0.f, 0.f, 0.f, 0.f};
    f32x4 acc1 = {0.f, 0.f, 0.f, 0.f};
    f32x4 acc2 = {0.f, 0.f, 0.f, 0.f};

    {
        int bufi = 0;
        STAGE(0, 0);
    }
    __syncthreads();

    #pragma unroll 2
    for (int k = 0; k < NCH; ++k) {
        if (k + 1 < NCH) {
            int bufi = (k + 1) & 1;
            STAGE(bufi, k + 1);
        }
        const char* buf = stage[k & 1];
        bf16x8 aH  = *(const bf16x8*)(buf + aoff);
        bf16x8 aL  = *(const bf16x8*)(buf + 4096 + aoff);
        bf16x8 bH0 = *(const bf16x8*)(buf + boff0);
        bf16x8 bL0 = *(const bf16x8*)(buf + 3072 + boff0);
        bf16x8 bH1 = *(const bf16x8*)(buf + boff1);
        bf16x8 bL1 = *(const bf16x8*)(buf + 3072 + boff1);
        bf16x8 bH2 = *(const bf16x8*)(buf + boff2);
        bf16x8 bL2 = *(const bf16x8*)(buf + 3072 + boff2);
        acc0 = __builtin_amdgcn_mfma_f32_16x16x32_bf16(aH, bH0, acc0, 0, 0, 0);
        acc1 = __builtin_amdgcn_mfma_f32_16x16x32_bf16(aH, bH1, acc1, 0, 0, 0);
        acc2 = __builtin_amdgcn_mfma_f32_16x16x32_bf16(aH, bH2, acc2, 0, 0, 0);
        acc0 = __builtin_amdgcn_mfma_f32_16x16x32_bf16(aH, bL0, acc0, 0, 0, 0);
        acc1 = __builtin_amdgcn_mfma_f32_16x16x32_bf16(aH, bL1, acc1, 0, 0, 0);
        acc2 = __builtin_amdgcn_mfma_f32_16x16x32_bf16(aH, bL2, acc2, 0, 0, 0);
        acc0 = __builtin_amdgcn_mfma_f32_16x16x32_bf16(aL, bH0, acc0, 0, 0, 0);
        acc1 = __builtin_amdgcn_mfma_f32_16x16x32_bf16(aL, bH1, acc1, 0, 0, 0);
        acc2 = __builtin_amdgcn_mfma_f32_16x16x32_bf16(aL, bH2, acc2, 0, 0, 0);
        __syncthreads();
    }

    // ---- scatter C into Lf[a_local][b_local][t][v] (overlays stage[0]) ----
    float* Lf = (float*)&stage[0][0];      // 12288 B
    {
        // C layout: row = (lane>>4)*4 + reg, col = lane&15
        #pragma unroll
        for (int r = 0; r < 4; ++r) {
            int Mrow0 = wid * 16 + kg4 * 4 + r;
            int al = Mrow0 >> 5, t = Mrow0 & 31;
            int c0 = 0 * 16 + r16, c1 = 1 * 16 + r16, c2 = 2 * 16 + r16;
            int bl0 = c0 / 12, bl1 = c1 / 12, bl2 = c2 / 12;
            Lf[((al * 4 + bl0) * T_ + t) * V_ + (c0 - bl0 * 12)] = acc0[r];
            Lf[((al * 4 + bl1) * T_ + t) * V_ + (c1 - bl1 * 12)] = acc1[r];
            Lf[((al * 4 + bl2) * T_ + t) * V_ + (c2 - bl2 * 12)] = acc2[r];
        }
    }
    __syncthreads();

    // ---- softmax phases: half-wave (32 lanes) per (a_local, b_local) pair ----
    const int p   = tid >> 5;          // 0..7
    const int l32 = tid & 31;
    const int al  = p >> 2, bl = p & 3;
    const float* Lrow = &Lf[((al * 4 + bl) * T_ + l32) * V_];

    // vps1 row softmax -> t2v (register)
    float t2v_val;
    {
        float l[V_];
        #pragma unroll
        for (int j = 0; j < V_; ++j) l[j] = Lrow[j];
        if (msh[al][l32]) {
            float m = -1e30f;
            #pragma unroll
            for (int j = 0; j < V_; ++j) m = fmaxf(m, l[j]);
            float s = 0.f, num = 0.f;
            #pragma unroll
            for (int j = 0; j < V_; ++j) {
                float e = expf(TAUF * (l[j] - m));
                s += e; num += e * l[j];
            }
            t2v_val = num / s;
        } else {
            // masked row: softmax of zeros = uniform -> mean of raw logits
            float s = 0.f;
            #pragma unroll
            for (int j = 0; j < V_; ++j) s += l[j];
            t2v_val = s * (1.0f / V_);
        }
    }

    // tps2 weights via width-32 shuffles; keep w2, W2 in registers
    bool  ex = (t2v_val == 0.0f);
    float xm = ex ? -1e30f : t2v_val;
    #pragma unroll
    for (int m = 16; m >= 1; m >>= 1) xm = fmaxf(xm, __shfl_xor(xm, m, 32));
    float w2 = ex ? 0.0f : expf(TAUF * (t2v_val - xm));
    float W2 = w2;
    #pragma unroll
    for (int m = 16; m >= 1; m >>= 1) W2 += __shfl_xor(W2, m, 32);

    // tps1 masked column softmax -> v2t_sh
    if (l32 < V_) {
        float m = -1e30f;
        for (int j = 0; j < T_; ++j) {
            float Lraw = Lf[((al * 4 + bl) * T_ + j) * V_ + l32];
            float Lm = msh[al][j] ? Lraw : 0.0f;
            if (Lm != 0.0f) m = fmaxf(m, Lm);
        }
        float s = 0.f, num = 0.f;
        for (int j = 0; j < T_; ++j) {
            float Lraw = Lf[((al * 4 + bl) * T_ + j) * V_ + l32];
            float Lm = msh[al][j] ? Lraw : 0.0f;
            if (Lm != 0.0f) {
                float e = expf(TAUF * (Lm - m));
                s += e; num += e * Lraw;
            }
        }
        v2t_sh[p][l32] = num / s;
    }
    __syncthreads();

    // vps2 weights
    if (l32 < V_) {
        float m = -1e30f;
        #pragma unroll
        for (int j = 0; j < V_; ++j) m = fmaxf(m, v2t_sh[p][j]);
        float s = 0.f;
        #pragma unroll
        for (int j = 0; j < V_; ++j) s += expf(TAUF * (v2t_sh[p][j] - m));
        wv_sh[p][l32] = expf(TAUF * (v2t_sh[p][l32] - m));
        if (l32 == 0) stats1[p] = s;
    }
    __syncthreads();

    // out = sum_{t,v} w2[t]*wv[v]*L[t,v] / (W2*Wv)
    {
        float pD = 0.f;
        #pragma unroll
        for (int j = 0; j < V_; ++j) pD += wv_sh[p][j] * Lrow[j];
        pD *= w2;
        #pragma unroll
        for (int m = 16; m >= 1; m >>= 1) pD += __shfl_xor(pD, m, 32);
        if (l32 == 0)
            out[(bm * 2 + al) * B_ + bn * 4 + bl] = pD / (W2 * stats1[p]);
    }
    #undef GLD16
}

extern "C" void kernel_launch(void* const* d_in, const int* in_sizes, int n_in,
                              void* d_out, int out_size, void* d_ws, size_t ws_size,
                              hipStream_t stream) {
    const float* text  = (const float*)d_in[0];
    const float* video = (const float*)d_in[1];
    const int*   mask  = (const int*)d_in[2];
    float* out = (float*)d_out;

    unsigned short* Apk = (unsigned short*)d_ws;              // 32*16*4096 ush = 4 MB
    unsigned short* Bpk = Apk + (size_t)32 * 16 * ABUF_USH;   // 16*16*3072 ush = 1.5 MB

    pack_kernel<<<704, 64, 0, stream>>>(text, video, Apk, Bpk);
    fused_kernel<<<512, 256, 0, stream>>>(Apk, Bpk, mask, out);
}

// Round 10
// 29.876 us; speedup vs baseline: 6.1287x; 1.0267x over previous
//
#include <hip/hip_runtime.h>
#include <math.h>

#define A_ 64
#define T_ 32
#define B_ 64
#define V_ 12
#define D_ 512
#define TAUF 100.0f

#define NCH 16             // K chunks of 32
// packed per-(bm,k) A buffer: hi[kg][64][8] 4096B | lo 4096B  = 4096 ush
// packed per-(bn,k) B buffer: hi[kg][48][8] 3072B | lo 3072B  = 3072 ush
#define ABUF_USH 4096
#define BBUF_USH 3072

typedef __attribute__((ext_vector_type(8))) short bf16x8;
typedef __attribute__((ext_vector_type(4))) float f32x4;

__device__ __forceinline__ unsigned short f2bf(float x) {
    unsigned int u = __float_as_uint(x);
    unsigned int r = (u + 0x7fffu + ((u >> 16) & 1u)) >> 16;   // RNE
    return (unsigned short)r;
}
__device__ __forceinline__ float bf2f(unsigned short h) {
    return __uint_as_float(((unsigned int)h) << 16);
}

// K1 (norm+pack): one wave per 4 rows; full-wave shfl reduce -> row norm;
// each lane splits its 8 elems into bf16 hi/lo and writes its 16B granule.
// Blocks 0..511: text rows. Blocks 512..703: video rows.
__global__ __launch_bounds__(64)
void pack_kernel(const float* __restrict__ text,
                 const float* __restrict__ video,
                 unsigned short* __restrict__ Apk,
                 unsigned short* __restrict__ Bpk)
{
    const int blk = blockIdx.x;
    const int l   = threadIdx.x;      // 0..63
    const int k   = l >> 2;           // k-chunk 0..15
    const int kg  = l & 3;            // k-group within chunk

    #pragma unroll
    for (int rr = 0; rr < 4; ++rr) {
        const float* src;
        unsigned short *obh, *obl;
        if (blk < 512) {
            int r = blk * 4 + rr;                 // 0..2047
            int bm = r >> 6, row = r & 63;
            src = text + (size_t)r * D_ + l * 8;
            unsigned short* base = Apk + ((size_t)(bm * 16 + k)) * ABUF_USH;
            obh = base + (kg * 64 + row) * 8;
            obl = obh + 2048;
        } else {
            int vr = (blk - 512) * 4 + rr;        // 0..767
            int bn = vr / 48, row = vr - bn * 48;
            src = video + (size_t)vr * D_ + l * 8;
            unsigned short* base = Bpk + ((size_t)(bn * 16 + k)) * BBUF_USH;
            obh = base + (kg * 48 + row) * 8;
            obl = obh + 1536;
        }
        float4 x0 = ((const float4*)src)[0];
        float4 x1 = ((const float4*)src)[1];
        float ss = x0.x * x0.x + x0.y * x0.y + x0.z * x0.z + x0.w * x0.w
                 + x1.x * x1.x + x1.y * x1.y + x1.z * x1.z + x1.w * x1.w;
        #pragma unroll
        for (int m = 32; m >= 1; m >>= 1) ss += __shfl_xor(ss, m);
        float inv = 1.0f / fmaxf(sqrtf(ss), 1e-6f);

        float y0 = x0.x * inv, y1 = x0.y * inv, y2 = x0.z * inv, y3 = x0.w * inv;
        float y4 = x1.x * inv, y5 = x1.y * inv, y6 = x1.z * inv, y7 = x1.w * inv;
        ushort4 h0, h1, l0, l1;
        h0.x = f2bf(y0); h0.y = f2bf(y1); h0.z = f2bf(y2); h0.w = f2bf(y3);
        h1.x = f2bf(y4); h1.y = f2bf(y5); h1.z = f2bf(y6); h1.w = f2bf(y7);
        l0.x = f2bf(y0 - bf2f(h0.x)); l0.y = f2bf(y1 - bf2f(h0.y));
        l0.z = f2bf(y2 - bf2f(h0.z)); l0.w = f2bf(y3 - bf2f(h0.w));
        l1.x = f2bf(y4 - bf2f(h1.x)); l1.y = f2bf(y5 - bf2f(h1.y));
        l1.z = f2bf(y6 - bf2f(h1.z)); l1.w = f2bf(y7 - bf2f(h1.w));
        ((ushort4*)obh)[0] = h0;
        ((ushort4*)obh)[1] = h1;
        ((ushort4*)obl)[0] = l0;
        ((ushort4*)obl)[1] = l1;
    }
}

// K2: 64x48 C-tile (2 a x 4 b), 4 waves. NO LDS staging, NO K-loop barriers:
// MFMA fragments load directly from the packed image (4x256B coalesced
// segments per load). XCD swizzle keeps the working set (~2MB) L2-local and
// pairs same-bn blocks on a CU for L1 reuse of B.
__global__ __launch_bounds__(256, 2)
void fused_kernel(const unsigned short* __restrict__ Apk,
                  const unsigned short* __restrict__ Bpk,
                  const int* __restrict__ mask,
                  float* __restrict__ out)
{
    const int wgid = blockIdx.x;      // 0..511
    const int xcd  = wgid & 7;
    const int i    = wgid >> 3;       // 0..63
    const int bm   = xcd * 4 + (i >> 4);   // 0..31
    const int bn   = i & 15;               // 0..15
    const int tid  = threadIdx.x;     // 0..255
    const int wid  = tid >> 6;
    const int lane = tid & 63;
    const int r16  = lane & 15;
    const int kg4  = lane >> 4;

    __shared__ float Lf[8 * T_ * V_];     // logits [al][bl][t][v], 12 KB
    __shared__ int   msh[2][T_];
    __shared__ float v2t_sh[8][V_];
    __shared__ float wv_sh[8][V_];
    __shared__ float stats1[8];

    if (tid < 64) msh[tid >> 5][tid & 31] = mask[(bm * 2 + (tid >> 5)) * T_ + (tid & 31)];

    // per-lane fragment base pointers into the packed image
    const unsigned short* Ab = Apk + (size_t)(bm * 16) * ABUF_USH
                                   + (kg4 * 64 + wid * 16 + r16) * 8;
    const unsigned short* Bb = Bpk + (size_t)(bn * 16) * BBUF_USH
                                   + (kg4 * 48 + r16) * 8;

    f32x4 acc0 = {0.f, 0.f, 0.f, 0.f};
    f32x4 acc1 = {0.f, 0.f, 0.f, 0.f};
    f32x4 acc2 = {0.f, 0.f, 0.f, 0.f};

    #pragma unroll 4
    for (int k = 0; k < NCH; ++k) {
        const unsigned short* a = Ab + k * ABUF_USH;
        const unsigned short* b = Bb + k * BBUF_USH;
        bf16x8 aH  = *(const bf16x8*)(a);
        bf16x8 aL  = *(const bf16x8*)(a + 2048);
        bf16x8 bH0 = *(const bf16x8*)(b);
        bf16x8 bH1 = *(const bf16x8*)(b + 128);
        bf16x8 bH2 = *(const bf16x8*)(b + 256);
        bf16x8 bL0 = *(const bf16x8*)(b + 1536);
        bf16x8 bL1 = *(const bf16x8*)(b + 1536 + 128);
        bf16x8 bL2 = *(const bf16x8*)(b + 1536 + 256);
        acc0 = __builtin_amdgcn_mfma_f32_16x16x32_bf16(aH, bH0, acc0, 0, 0, 0);
        acc1 = __builtin_amdgcn_mfma_f32_16x16x32_bf16(aH, bH1, acc1, 0, 0, 0);
        acc2 = __builtin_amdgcn_mfma_f32_16x16x32_bf16(aH, bH2, acc2, 0, 0, 0);
        acc0 = __builtin_amdgcn_mfma_f32_16x16x32_bf16(aH, bL0, acc0, 0, 0, 0);
        acc1 = __builtin_amdgcn_mfma_f32_16x16x32_bf16(aH, bL1, acc1, 0, 0, 0);
        acc2 = __builtin_amdgcn_mfma_f32_16x16x32_bf16(aH, bL2, acc2, 0, 0, 0);
        acc0 = __builtin_amdgcn_mfma_f32_16x16x32_bf16(aL, bH0, acc0, 0, 0, 0);
        acc1 = __builtin_amdgcn_mfma_f32_16x16x32_bf16(aL, bH1, acc1, 0, 0, 0);
        acc2 = __builtin_amdgcn_mfma_f32_16x16x32_bf16(aL, bH2, acc2, 0, 0, 0);
    }

    // ---- scatter C into Lf[al][bl][t][v] ----
    {
        // C layout: row = (lane>>4)*4 + reg, col = lane&15
        #pragma unroll
        for (int r = 0; r < 4; ++r) {
            int Mrow0 = wid * 16 + kg4 * 4 + r;
            int al = Mrow0 >> 5, t = Mrow0 & 31;
            int c0 = 0 * 16 + r16, c1 = 1 * 16 + r16, c2 = 2 * 16 + r16;
            int bl0 = c0 / 12, bl1 = c1 / 12, bl2 = c2 / 12;
            Lf[((al * 4 + bl0) * T_ + t) * V_ + (c0 - bl0 * 12)] = acc0[r];
            Lf[((al * 4 + bl1) * T_ + t) * V_ + (c1 - bl1 * 12)] = acc1[r];
            Lf[((al * 4 + bl2) * T_ + t) * V_ + (c2 - bl2 * 12)] = acc2[r];
        }
    }
    __syncthreads();

    // ---- softmax phases: half-wave (32 lanes) per (al, bl) pair ----
    const int p   = tid >> 5;          // 0..7
    const int l32 = tid & 31;
    const int al  = p >> 2, bl = p & 3;
    const float* Lrow = &Lf[((al * 4 + bl) * T_ + l32) * V_];

    // vps1 row softmax -> t2v (register)
    float t2v_val;
    {
        float l[V_];
        #pragma unroll
        for (int j = 0; j < V_; ++j) l[j] = Lrow[j];
        if (msh[al][l32]) {
            float m = -1e30f;
            #pragma unroll
            for (int j = 0; j < V_; ++j) m = fmaxf(m, l[j]);
            float s = 0.f, num = 0.f;
            #pragma unroll
            for (int j = 0; j < V_; ++j) {
                float e = expf(TAUF * (l[j] - m));
                s += e; num += e * l[j];
            }
            t2v_val = num / s;
        } else {
            // masked row: softmax of zeros = uniform -> mean of raw logits
            float s = 0.f;
            #pragma unroll
            for (int j = 0; j < V_; ++j) s += l[j];
            t2v_val = s * (1.0f / V_);
        }
    }

    // tps2 weights via width-32 shuffles; keep w2, W2 in registers
    bool  ex = (t2v_val == 0.0f);
    float xm = ex ? -1e30f : t2v_val;
    #pragma unroll
    for (int m = 16; m >= 1; m >>= 1) xm = fmaxf(xm, __shfl_xor(xm, m, 32));
    float w2 = ex ? 0.0f : expf(TAUF * (t2v_val - xm));
    float W2 = w2;
    #pragma unroll
    for (int m = 16; m >= 1; m >>= 1) W2 += __shfl_xor(W2, m, 32);

    // tps1 masked column softmax -> v2t_sh
    if (l32 < V_) {
        float m = -1e30f;
        for (int j = 0; j < T_; ++j) {
            float Lraw = Lf[((al * 4 + bl) * T_ + j) * V_ + l32];
            float Lm = msh[al][j] ? Lraw : 0.0f;
            if (Lm != 0.0f) m = fmaxf(m, Lm);
        }
        float s = 0.f, num = 0.f;
        for (int j = 0; j < T_; ++j) {
            float Lraw = Lf[((al * 4 + bl) * T_ + j) * V_ + l32];
            float Lm = msh[al][j] ? Lraw : 0.0f;
            if (Lm != 0.0f) {
                float e = expf(TAUF * (Lm - m));
                s += e; num += e * Lraw;
            }
        }
        v2t_sh[p][l32] = num / s;
    }
    __syncthreads();

    // vps2 weights
    if (l32 < V_) {
        float m = -1e30f;
        #pragma unroll
        for (int j = 0; j < V_; ++j) m = fmaxf(m, v2t_sh[p][j]);
        float s = 0.f;
        #pragma unroll
        for (int j = 0; j < V_; ++j) s += expf(TAUF * (v2t_sh[p][j] - m));
        wv_sh[p][l32] = expf(TAUF * (v2t_sh[p][l32] - m));
        if (l32 == 0) stats1[p] = s;
    }
    __syncthreads();

    // out = sum_{t,v} w2[t]*wv[v]*L[t,v] / (W2*Wv)
    {
        float pD = 0.f;
        #pragma unroll
        for (int j = 0; j < V_; ++j) pD += wv_sh[p][j] * Lrow[j];
        pD *= w2;
        #pragma unroll
        for (int m = 16; m >= 1; m >>= 1) pD += __shfl_xor(pD, m, 32);
        if (l32 == 0)
            out[(bm * 2 + al) * B_ + bn * 4 + bl] = pD / (W2 * stats1[p]);
    }
}

extern "C" void kernel_launch(void* const* d_in, const int* in_sizes, int n_in,
                              void* d_out, int out_size, void* d_ws, size_t ws_size,
                              hipStream_t stream) {
    const float* text  = (const float*)d_in[0];
    const float* video = (const float*)d_in[1];
    const int*   mask  = (const int*)d_in[2];
    float* out = (float*)d_out;

    unsigned short* Apk = (unsigned short*)d_ws;              // 32*16*4096 ush = 4 MB
    unsigned short* Bpk = Apk + (size_t)32 * 16 * ABUF_USH;   // 16*16*3072 ush = 1.5 MB

    pack_kernel<<<704, 64, 0, stream>>>(text, video, Apk, Bpk);
    fused_kernel<<<512, 256, 0, stream>>>(Apk, Bpk, mask, out);
}

// Round 11
// 27.905 us; speedup vs baseline: 6.5616x; 1.0706x over previous
//
#include <hip/hip_runtime.h>
#include <math.h>

#define A_ 64
#define T_ 32
#define B_ 64
#define V_ 12
#define D_ 512
#define TAUF 100.0f
#define NCH 16             // K chunks of 32

// stage buffer layout (bytes): A_hi[kg][64][8] 4096 | A_lo 4096 |
//                              B_hi[kg][48][8] 3072 | B_lo 3072  = 14336
#define BUFBYTES 14336

typedef __attribute__((ext_vector_type(8))) short bf16x8;
typedef __attribute__((ext_vector_type(4))) float f32x4;

__device__ __forceinline__ unsigned short f2bf(float x) {
    unsigned int u = __float_as_uint(x);
    unsigned int r = (u + 0x7fffu + ((u >> 16) & 1u)) >> 16;   // RNE
    return (unsigned short)r;
}
__device__ __forceinline__ float bf2f(unsigned short h) {
    return __uint_as_float(((unsigned int)h) << 16);
}

// split 8 raw floats into bf16 hi/lo vectors, accumulate sum of squares
__device__ __forceinline__ void split8(const float4 x0, const float4 x1,
                                       bf16x8& hv, bf16x8& lv, float& ss)
{
    float y[8] = {x0.x, x0.y, x0.z, x0.w, x1.x, x1.y, x1.z, x1.w};
    #pragma unroll
    for (int j = 0; j < 8; ++j) {
        ss += y[j] * y[j];
        unsigned short h = f2bf(y[j]);
        hv[j] = (short)h;
        lv[j] = (short)f2bf(y[j] - bf2f(h));
    }
}

// Single kernel: block = 64x48 C-tile (2 a x 4 b), 4 waves.
// Per K-chunk: in-block pack of RAW text/video (bf16 hi/lo) into LDS dbuf,
// 9 MFMAs; norms accumulated in-register during packing (normalization is a
// rank-1 scaling -> applied at C-scatter). XCD swizzle keeps panels L2-local.
__global__ __launch_bounds__(256)
void fused_kernel(const float* __restrict__ text,
                  const float* __restrict__ video,
                  const int* __restrict__ mask,
                  float* __restrict__ out)
{
    const int wgid = blockIdx.x;      // 0..511
    const int xcd  = wgid & 7;
    const int i    = wgid >> 3;
    const int bm   = xcd * 4 + (i >> 4);   // 0..31
    const int bn   = i & 15;               // 0..15
    const int tid  = threadIdx.x;     // 0..255
    const int wid  = tid >> 6;
    const int lane = tid & 63;
    const int r16  = lane & 15;
    const int kg4  = lane >> 4;

    __shared__ __align__(16) char stage[2][BUFBYTES];
    __shared__ float nrmA[4][64];
    __shared__ float nrmB[4][48];
    __shared__ float invA[64];
    __shared__ float invB[48];
    __shared__ int   msh[2][T_];
    __shared__ float v2t_sh[8][V_];
    __shared__ float wv_sh[8][V_];
    __shared__ float stats1[8];

    if (tid < 64) msh[tid >> 5][tid & 31] = mask[(bm * 2 + (tid >> 5)) * T_ + (tid & 31)];

    // pack assignments: thread owns one A granule (row arow, k-group akg) and,
    // for tid<192, one B granule. Same granule across all 16 chunks.
    const int arow = tid & 63, akg = tid >> 6;
    const float* asrc = text + ((size_t)(bm * 64 + arow)) * D_ + akg * 8;
    const int bq   = (tid < 192) ? tid : 0;
    const int bkg  = bq / 48, brow = bq - bkg * 48;
    const float* bsrc = video + ((size_t)(bn * 48 + brow)) * D_ + bkg * 8;

    float ssA = 0.f, ssB = 0.f;

    auto PACK = [&](int bufi, int k) {
        char* buf = stage[bufi];
        {
            const float4* s = (const float4*)(asrc + k * 32);
            float4 x0 = s[0], x1 = s[1];
            bf16x8 hv, lv;
            split8(x0, x1, hv, lv, ssA);
            *(bf16x8*)(buf + tid * 16)        = hv;   // A-hi
            *(bf16x8*)(buf + 4096 + tid * 16) = lv;   // A-lo
        }
        if (tid < 192) {
            const float4* s = (const float4*)(bsrc + k * 32);
            float4 x0 = s[0], x1 = s[1];
            bf16x8 hv, lv;
            split8(x0, x1, hv, lv, ssB);
            *(bf16x8*)(buf + 8192 + tid * 16)  = hv;  // B-hi
            *(bf16x8*)(buf + 11264 + tid * 16) = lv;  // B-lo
        }
    };

    // fragment byte offsets within a stage buffer (2-way bank aliasing = free)
    const int aoff  = (kg4 * 64 + wid * 16 + r16) * 16;
    const int boff0 = 8192 + (kg4 * 48 + 0 * 16 + r16) * 16;
    const int boff1 = 8192 + (kg4 * 48 + 1 * 16 + r16) * 16;
    const int boff2 = 8192 + (kg4 * 48 + 2 * 16 + r16) * 16;

    f32x4 acc0 = {0.f, 0.f, 0.f, 0.f};
    f32x4 acc1 = {0.f, 0.f, 0.f, 0.f};
    f32x4 acc2 = {0.f, 0.f, 0.f, 0.f};

    PACK(0, 0);
    __syncthreads();

    #pragma unroll 2
    for (int k = 0; k < NCH; ++k) {
        if (k + 1 < NCH) PACK((k + 1) & 1, k + 1);
        const char* buf = stage[k & 1];
        bf16x8 aH  = *(const bf16x8*)(buf + aoff);
        bf16x8 aL  = *(const bf16x8*)(buf + 4096 + aoff);
        bf16x8 bH0 = *(const bf16x8*)(buf + boff0);
        bf16x8 bL0 = *(const bf16x8*)(buf + 3072 + boff0);
        bf16x8 bH1 = *(const bf16x8*)(buf + boff1);
        bf16x8 bL1 = *(const bf16x8*)(buf + 3072 + boff1);
        bf16x8 bH2 = *(const bf16x8*)(buf + boff2);
        bf16x8 bL2 = *(const bf16x8*)(buf + 3072 + boff2);
        acc0 = __builtin_amdgcn_mfma_f32_16x16x32_bf16(aH, bH0, acc0, 0, 0, 0);
        acc1 = __builtin_amdgcn_mfma_f32_16x16x32_bf16(aH, bH1, acc1, 0, 0, 0);
        acc2 = __builtin_amdgcn_mfma_f32_16x16x32_bf16(aH, bH2, acc2, 0, 0, 0);
        acc0 = __builtin_amdgcn_mfma_f32_16x16x32_bf16(aH, bL0, acc0, 0, 0, 0);
        acc1 = __builtin_amdgcn_mfma_f32_16x16x32_bf16(aH, bL1, acc1, 0, 0, 0);
        acc2 = __builtin_amdgcn_mfma_f32_16x16x32_bf16(aH, bL2, acc2, 0, 0, 0);
        acc0 = __builtin_amdgcn_mfma_f32_16x16x32_bf16(aL, bH0, acc0, 0, 0, 0);
        acc1 = __builtin_amdgcn_mfma_f32_16x16x32_bf16(aL, bH1, acc1, 0, 0, 0);
        acc2 = __builtin_amdgcn_mfma_f32_16x16x32_bf16(aL, bH2, acc2, 0, 0, 0);
        __syncthreads();
    }

    // ---- norm reduction: 4 quarter-row partials -> inverse norms ----
    nrmA[akg][arow] = ssA;
    if (tid < 192) nrmB[bkg][brow] = ssB;
    __syncthreads();
    if (tid < 64) {
        float s = nrmA[0][tid] + nrmA[1][tid] + nrmA[2][tid] + nrmA[3][tid];
        invA[tid] = 1.0f / fmaxf(sqrtf(s), 1e-6f);
    } else if (tid < 112) {
        int r = tid - 64;
        float s = nrmB[0][r] + nrmB[1][r] + nrmB[2][r] + nrmB[3][r];
        invB[r] = 1.0f / fmaxf(sqrtf(s), 1e-6f);
    }
    __syncthreads();

    // ---- scatter C (scaled by invA*invB) into Lf[al][bl][t][v] ----
    float* Lf = (float*)&stage[0][0];      // 12288 B overlay
    {
        // C layout: row = (lane>>4)*4 + reg, col = lane&15
        #pragma unroll
        for (int r = 0; r < 4; ++r) {
            int Mrow0 = wid * 16 + kg4 * 4 + r;
            int al = Mrow0 >> 5, t = Mrow0 & 31;
            float ia = invA[Mrow0];
            int c0 = r16, c1 = 16 + r16, c2 = 32 + r16;
            int bl0 = c0 / 12, bl1 = c1 / 12, bl2 = c2 / 12;
            Lf[((al * 4 + bl0) * T_ + t) * V_ + (c0 - bl0 * 12)] = acc0[r] * ia * invB[c0];
            Lf[((al * 4 + bl1) * T_ + t) * V_ + (c1 - bl1 * 12)] = acc1[r] * ia * invB[c1];
            Lf[((al * 4 + bl2) * T_ + t) * V_ + (c2 - bl2 * 12)] = acc2[r] * ia * invB[c2];
        }
    }
    __syncthreads();

    // ---- softmax phases: half-wave (32 lanes) per (al, bl) pair ----
    const int p   = tid >> 5;          // 0..7
    const int l32 = tid & 31;
    const int al  = p >> 2, bl = p & 3;
    const float* Lrow = &Lf[((al * 4 + bl) * T_ + l32) * V_];

    // vps1 row softmax -> t2v (register)
    float t2v_val;
    {
        float l[V_];
        #pragma unroll
        for (int j = 0; j < V_; ++j) l[j] = Lrow[j];
        if (msh[al][l32]) {
            float m = -1e30f;
            #pragma unroll
            for (int j = 0; j < V_; ++j) m = fmaxf(m, l[j]);
            float s = 0.f, num = 0.f;
            #pragma unroll
            for (int j = 0; j < V_; ++j) {
                float e = expf(TAUF * (l[j] - m));
                s += e; num += e * l[j];
            }
            t2v_val = num / s;
        } else {
            // masked row: softmax of zeros = uniform -> mean of raw logits
            float s = 0.f;
            #pragma unroll
            for (int j = 0; j < V_; ++j) s += l[j];
            t2v_val = s * (1.0f / V_);
        }
    }

    // tps2 weights via width-32 shuffles; keep w2, W2 in registers
    bool  ex = (t2v_val == 0.0f);
    float xm = ex ? -1e30f : t2v_val;
    #pragma unroll
    for (int m = 16; m >= 1; m >>= 1) xm = fmaxf(xm, __shfl_xor(xm, m, 32));
    float w2 = ex ? 0.0f : expf(TAUF * (t2v_val - xm));
    float W2 = w2;
    #pragma unroll
    for (int m = 16; m >= 1; m >>= 1) W2 += __shfl_xor(W2, m, 32);

    // tps1 masked column softmax -> v2t_sh
    if (l32 < V_) {
        float m = -1e30f;
        for (int j = 0; j < T_; ++j) {
            float Lraw = Lf[((al * 4 + bl) * T_ + j) * V_ + l32];
            float Lm = msh[al][j] ? Lraw : 0.0f;
            if (Lm != 0.0f) m = fmaxf(m, Lm);
        }
        float s = 0.f, num = 0.f;
        for (int j = 0; j < T_; ++j) {
            float Lraw = Lf[((al * 4 + bl) * T_ + j) * V_ + l32];
            float Lm = msh[al][j] ? Lraw : 0.0f;
            if (Lm != 0.0f) {
                float e = expf(TAUF * (Lm - m));
                s += e; num += e * Lraw;
            }
        }
        v2t_sh[p][l32] = num / s;
    }
    __syncthreads();

    // vps2 weights
    if (l32 < V_) {
        float m = -1e30f;
        #pragma unroll
        for (int j = 0; j < V_; ++j) m = fmaxf(m, v2t_sh[p][j]);
        float s = 0.f;
        #pragma unroll
        for (int j = 0; j < V_; ++j) s += expf(TAUF * (v2t_sh[p][j] - m));
        wv_sh[p][l32] = expf(TAUF * (v2t_sh[p][l32] - m));
        if (l32 == 0) stats1[p] = s;
    }
    __syncthreads();

    // out = sum_{t,v} w2[t]*wv[v]*L[t,v] / (W2*Wv)
    {
        float pD = 0.f;
        #pragma unroll
        for (int j = 0; j < V_; ++j) pD += wv_sh[p][j] * Lrow[j];
        pD *= w2;
        #pragma unroll
        for (int m = 16; m >= 1; m >>= 1) pD += __shfl_xor(pD, m, 32);
        if (l32 == 0)
            out[(bm * 2 + al) * B_ + bn * 4 + bl] = pD / (W2 * stats1[p]);
    }
}

extern "C" void kernel_launch(void* const* d_in, const int* in_sizes, int n_in,
                              void* d_out, int out_size, void* d_ws, size_t ws_size,
                              hipStream_t stream) {
    const float* text  = (const float*)d_in[0];
    const float* video = (const float*)d_in[1];
    const int*   mask  = (const int*)d_in[2];
    float* out = (float*)d_out;

    fused_kernel<<<512, 256, 0, stream>>>(text, video, mask, out);
}

// Round 12
// 20.715 us; speedup vs baseline: 8.8392x; 1.3471x over previous
//
#include <hip/hip_runtime.h>
#include <math.h>

#define A_ 64
#define T_ 32
#define B_ 64
#define V_ 12
#define D_ 512
#define TAUF 100.0f
#define NCH 8              // K chunks of 64

// stage buffer layout (bytes): A_hi[kg8][64][16] 8192 | A_lo 8192 |
//                              B_hi[kg8][48][16] 6144 | B_lo 6144  = 28672
#define AHI 0
#define ALO 8192
#define BHI 16384
#define BLO 22528
#define BUFBYTES 28672

typedef __attribute__((ext_vector_type(8))) short bf16x8;
typedef __attribute__((ext_vector_type(4))) float f32x4;

// truncation split: hi = top 16 bits of f32, lo = trunc(y - hi). ~5 VALU/elem.
__device__ __forceinline__ void splitT(const float4 x0, const float4 x1,
                                       bf16x8& hv, bf16x8& lv, float& ss)
{
    float y[8] = {x0.x, x0.y, x0.z, x0.w, x1.x, x1.y, x1.z, x1.w};
    #pragma unroll
    for (int j = 0; j < 8; ++j) {
        ss += y[j] * y[j];
        unsigned int u = __float_as_uint(y[j]);
        float hf = __uint_as_float(u & 0xffff0000u);
        hv[j] = (short)(u >> 16);
        lv[j] = (short)(__float_as_uint(y[j] - hf) >> 16);
    }
}

// Single kernel: block = 64x48 C-tile (2 a x 4 b), 4 waves, BK=64 dbuf.
// Pack loads are memory-linear (coalesced 2KB/wave-load); LDS slots are
// XOR-swizzled (slot = kg*N + (row^kg)) so pack writes hit 8 distinct bank
// quads and fragment reads stay conflict-free. Norms accumulate in-register
// during packing; normalization applied at C-scatter (rank-1 scaling).
__global__ __launch_bounds__(256)
void fused_kernel(const float* __restrict__ text,
                  const float* __restrict__ video,
                  const int* __restrict__ mask,
                  float* __restrict__ out)
{
    const int wgid = blockIdx.x;      // 0..511
    const int xcd  = wgid & 7;
    const int i    = wgid >> 3;
    const int bm   = xcd * 4 + (i >> 4);   // 0..31
    const int bn   = i & 15;               // 0..15
    const int tid  = threadIdx.x;     // 0..255
    const int wid  = tid >> 6;
    const int lane = tid & 63;
    const int r16  = lane & 15;
    const int kg4  = lane >> 4;

    __shared__ __align__(16) char stage[2][BUFBYTES];
    __shared__ float nrmA[8][64];
    __shared__ float nrmB[8][48];
    __shared__ float invA[64];
    __shared__ float invB[48];
    __shared__ int   msh[2][T_];
    __shared__ float v2t_sh[8][V_];
    __shared__ float wv_sh[8][V_];
    __shared__ float stats1[8];

    if (tid < 64) msh[tid >> 5][tid & 31] = mask[(bm * 2 + (tid >> 5)) * T_ + (tid & 31)];

    // pack granule assignments (memory-linear: coalesced global reads)
    const int arow0 = tid >> 3, akg = tid & 7;        // A granules tid, tid+256
    const int arow1 = arow0 + 32;
    const float* asrc0 = text + ((size_t)(bm * 64 + arow0)) * D_ + akg * 8;
    const float* asrc1 = text + ((size_t)(bm * 64 + arow1)) * D_ + akg * 8;
    const int brow0 = tid >> 3, bkg = tid & 7;        // B granules tid, tid+192 (tid<192)
    const int brow1 = brow0 + 24;
    const float* bsrc0 = video + ((size_t)(bn * 48 + brow0)) * D_ + bkg * 8;
    const float* bsrc1 = video + ((size_t)(bn * 48 + brow1)) * D_ + bkg * 8;

    // swizzled LDS byte offsets for pack writes
    const int adst0 = (akg * 64 + (arow0 ^ akg)) * 16;
    const int adst1 = (akg * 64 + (arow1 ^ akg)) * 16;
    const int bdst0 = BHI + (bkg * 48 + (brow0 ^ bkg)) * 16;
    const int bdst1 = BHI + (bkg * 48 + (brow1 ^ bkg)) * 16;

    float ssA0 = 0.f, ssA1 = 0.f, ssB0 = 0.f, ssB1 = 0.f;

    auto PACK = [&](int bufi, int k) {
        char* buf = stage[bufi];
        {
            const float4* s = (const float4*)(asrc0 + k * 64);
            bf16x8 hv, lv;
            splitT(s[0], s[1], hv, lv, ssA0);
            *(bf16x8*)(buf + adst0)       = hv;
            *(bf16x8*)(buf + ALO + adst0) = lv;
        }
        {
            const float4* s = (const float4*)(asrc1 + k * 64);
            bf16x8 hv, lv;
            splitT(s[0], s[1], hv, lv, ssA1);
            *(bf16x8*)(buf + adst1)       = hv;
            *(bf16x8*)(buf + ALO + adst1) = lv;
        }
        if (tid < 192) {
            {
                const float4* s = (const float4*)(bsrc0 + k * 64);
                bf16x8 hv, lv;
                splitT(s[0], s[1], hv, lv, ssB0);
                *(bf16x8*)(buf + bdst0)             = hv;
                *(bf16x8*)(buf + (BLO - BHI) + bdst0) = lv;
            }
            {
                const float4* s = (const float4*)(bsrc1 + k * 64);
                bf16x8 hv, lv;
                splitT(s[0], s[1], hv, lv, ssB1);
                *(bf16x8*)(buf + bdst1)             = hv;
                *(bf16x8*)(buf + (BLO - BHI) + bdst1) = lv;
            }
        }
    };

    // swizzled fragment byte offsets (s = k-step 0/1 within chunk)
    const int rowa = wid * 16 + r16;
    int aoff[2], boff[2][3];
    #pragma unroll
    for (int s = 0; s < 2; ++s) {
        int kg = s * 4 + kg4;
        aoff[s] = (kg * 64 + (rowa ^ kg)) * 16;
        #pragma unroll
        for (int c = 0; c < 3; ++c) {
            int rowb = c * 16 + r16;
            boff[s][c] = BHI + (kg * 48 + (rowb ^ kg)) * 16;
        }
    }

    f32x4 acc0 = {0.f, 0.f, 0.f, 0.f};
    f32x4 acc1 = {0.f, 0.f, 0.f, 0.f};
    f32x4 acc2 = {0.f, 0.f, 0.f, 0.f};

    PACK(0, 0);
    __syncthreads();

    #pragma unroll 2
    for (int k = 0; k < NCH; ++k) {
        if (k + 1 < NCH) PACK((k + 1) & 1, k + 1);
        const char* buf = stage[k & 1];
        #pragma unroll
        for (int s = 0; s < 2; ++s) {
            bf16x8 aH  = *(const bf16x8*)(buf + aoff[s]);
            bf16x8 aL  = *(const bf16x8*)(buf + ALO + aoff[s]);
            bf16x8 bH0 = *(const bf16x8*)(buf + boff[s][0]);
            bf16x8 bL0 = *(const bf16x8*)(buf + (BLO - BHI) + boff[s][0]);
            bf16x8 bH1 = *(const bf16x8*)(buf + boff[s][1]);
            bf16x8 bL1 = *(const bf16x8*)(buf + (BLO - BHI) + boff[s][1]);
            bf16x8 bH2 = *(const bf16x8*)(buf + boff[s][2]);
            bf16x8 bL2 = *(const bf16x8*)(buf + (BLO - BHI) + boff[s][2]);
            acc0 = __builtin_amdgcn_mfma_f32_16x16x32_bf16(aH, bH0, acc0, 0, 0, 0);
            acc1 = __builtin_amdgcn_mfma_f32_16x16x32_bf16(aH, bH1, acc1, 0, 0, 0);
            acc2 = __builtin_amdgcn_mfma_f32_16x16x32_bf16(aH, bH2, acc2, 0, 0, 0);
            acc0 = __builtin_amdgcn_mfma_f32_16x16x32_bf16(aH, bL0, acc0, 0, 0, 0);
            acc1 = __builtin_amdgcn_mfma_f32_16x16x32_bf16(aH, bL1, acc1, 0, 0, 0);
            acc2 = __builtin_amdgcn_mfma_f32_16x16x32_bf16(aH, bL2, acc2, 0, 0, 0);
            acc0 = __builtin_amdgcn_mfma_f32_16x16x32_bf16(aL, bH0, acc0, 0, 0, 0);
            acc1 = __builtin_amdgcn_mfma_f32_16x16x32_bf16(aL, bH1, acc1, 0, 0, 0);
            acc2 = __builtin_amdgcn_mfma_f32_16x16x32_bf16(aL, bH2, acc2, 0, 0, 0);
        }
        __syncthreads();
    }

    // ---- norm reduction: 8 partials per row -> inverse norms ----
    nrmA[akg][arow0] = ssA0;
    nrmA[akg][arow1] = ssA1;
    if (tid < 192) { nrmB[bkg][brow0] = ssB0; nrmB[bkg][brow1] = ssB1; }
    __syncthreads();
    if (tid < 64) {
        float s = 0.f;
        #pragma unroll
        for (int j = 0; j < 8; ++j) s += nrmA[j][tid];
        invA[tid] = 1.0f / fmaxf(sqrtf(s), 1e-6f);
    } else if (tid < 112) {
        int r = tid - 64;
        float s = 0.f;
        #pragma unroll
        for (int j = 0; j < 8; ++j) s += nrmB[j][r];
        invB[r] = 1.0f / fmaxf(sqrtf(s), 1e-6f);
    }
    __syncthreads();

    // ---- scatter C (scaled by invA*invB) into Lf[al][bl][t][v] ----
    float* Lf = (float*)&stage[0][0];      // 12288 B overlay
    {
        // C layout: row = (lane>>4)*4 + reg, col = lane&15
        #pragma unroll
        for (int r = 0; r < 4; ++r) {
            int Mrow0 = wid * 16 + kg4 * 4 + r;
            int al = Mrow0 >> 5, t = Mrow0 & 31;
            float ia = invA[Mrow0];
            int c0 = r16, c1 = 16 + r16, c2 = 32 + r16;
            int bl0 = c0 / 12, bl1 = c1 / 12, bl2 = c2 / 12;
            Lf[((al * 4 + bl0) * T_ + t) * V_ + (c0 - bl0 * 12)] = acc0[r] * ia * invB[c0];
            Lf[((al * 4 + bl1) * T_ + t) * V_ + (c1 - bl1 * 12)] = acc1[r] * ia * invB[c1];
            Lf[((al * 4 + bl2) * T_ + t) * V_ + (c2 - bl2 * 12)] = acc2[r] * ia * invB[c2];
        }
    }
    __syncthreads();

    // ---- softmax phases: half-wave (32 lanes) per (al, bl) pair ----
    const int p   = tid >> 5;          // 0..7
    const int l32 = tid & 31;
    const int al  = p >> 2, bl = p & 3;
    const float* Lrow = &Lf[((al * 4 + bl) * T_ + l32) * V_];

    // vps1 row softmax -> t2v (register)
    float t2v_val;
    {
        float l[V_];
        #pragma unroll
        for (int j = 0; j < V_; ++j) l[j] = Lrow[j];
        if (msh[al][l32]) {
            float m = -1e30f;
            #pragma unroll
            for (int j = 0; j < V_; ++j) m = fmaxf(m, l[j]);
            float s = 0.f, num = 0.f;
            #pragma unroll
            for (int j = 0; j < V_; ++j) {
                float e = expf(TAUF * (l[j] - m));
                s += e; num += e * l[j];
            }
            t2v_val = num / s;
        } else {
            // masked row: softmax of zeros = uniform -> mean of raw logits
            float s = 0.f;
            #pragma unroll
            for (int j = 0; j < V_; ++j) s += l[j];
            t2v_val = s * (1.0f / V_);
        }
    }

    // tps2 weights via width-32 shuffles; keep w2, W2 in registers
    bool  ex = (t2v_val == 0.0f);
    float xm = ex ? -1e30f : t2v_val;
    #pragma unroll
    for (int m = 16; m >= 1; m >>= 1) xm = fmaxf(xm, __shfl_xor(xm, m, 32));
    float w2 = ex ? 0.0f : expf(TAUF * (t2v_val - xm));
    float W2 = w2;
    #pragma unroll
    for (int m = 16; m >= 1; m >>= 1) W2 += __shfl_xor(W2, m, 32);

    // tps1 masked column softmax -> v2t_sh
    if (l32 < V_) {
        float m = -1e30f;
        for (int j = 0; j < T_; ++j) {
            float Lraw = Lf[((al * 4 + bl) * T_ + j) * V_ + l32];
            float Lm = msh[al][j] ? Lraw : 0.0f;
            if (Lm != 0.0f) m = fmaxf(m, Lm);
        }
        float s = 0.f, num = 0.f;
        for (int j = 0; j < T_; ++j) {
            float Lraw = Lf[((al * 4 + bl) * T_ + j) * V_ + l32];
            float Lm = msh[al][j] ? Lraw : 0.0f;
            if (Lm != 0.0f) {
                float e = expf(TAUF * (Lm - m));
                s += e; num += e * Lraw;
            }
        }
        v2t_sh[p][l32] = num / s;
    }
    __syncthreads();

    // vps2 weights
    if (l32 < V_) {
        float m = -1e30f;
        #pragma unroll
        for (int j = 0; j < V_; ++j) m = fmaxf(m, v2t_sh[p][j]);
        float s = 0.f;
        #pragma unroll
        for (int j = 0; j < V_; ++j) s += expf(TAUF * (v2t_sh[p][j] - m));
        wv_sh[p][l32] = expf(TAUF * (v2t_sh[p][l32] - m));
        if (l32 == 0) stats1[p] = s;
    }
    __syncthreads();

    // out = sum_{t,v} w2[t]*wv[v]*L[t,v] / (W2*Wv)
    {
        float pD = 0.f;
        #pragma unroll
        for (int j = 0; j < V_; ++j) pD += wv_sh[p][j] * Lrow[j];
        pD *= w2;
        #pragma unroll
        for (int m = 16; m >= 1; m >>= 1) pD += __shfl_xor(pD, m, 32);
        if (l32 == 0)
            out[(bm * 2 + al) * B_ + bn * 4 + bl] = pD / (W2 * stats1[p]);
    }
}

extern "C" void kernel_launch(void* const* d_in, const int* in_sizes, int n_in,
                              void* d_out, int out_size, void* d_ws, size_t ws_size,
                              hipStream_t stream) {
    const float* text  = (const float*)d_in[0];
    const float* video = (const float*)d_in[1];
    const int*   mask  = (const int*)d_in[2];
    float* out = (float*)d_out;

    fused_kernel<<<512, 256, 0, stream>>>(text, video, mask, out);
}